// Round 16
// baseline (245.643 us; speedup 1.0000x reference)
//
#include <hip/hip_runtime.h>
#include <hip/hip_bf16.h>
#include <math.h>

typedef __bf16 bf16;
typedef __attribute__((ext_vector_type(8))) __bf16 bf16x8;
typedef __attribute__((ext_vector_type(4))) __bf16 bf16x4;
typedef __attribute__((ext_vector_type(4))) float f32x4;

#define DEV static __device__ __forceinline__

typedef const void __attribute__((address_space(1)))* gptr_t;
typedef void __attribute__((address_space(3)))* lptr_t;

DEV void async16(const void* g, void* l) {
  __builtin_amdgcn_global_load_lds((gptr_t)g, (lptr_t)l, 16, 0, 0);
}

DEV void wg_barrier() {
  __builtin_amdgcn_sched_barrier(0);
  __builtin_amdgcn_s_barrier();
  __builtin_amdgcn_sched_barrier(0);
}

// ---------------- fused fp32 -> bf16 convert (4 weight arrays) ----------------
__global__ __launch_bounds__(256) void f2b4_kernel(const float* __restrict__ s0,
                                                   const float* __restrict__ s1,
                                                   const float* __restrict__ s2,
                                                   const float* __restrict__ s3,
                                                   bf16* __restrict__ d0, bf16* __restrict__ d1,
                                                   bf16* __restrict__ d2, bf16* __restrict__ d3,
                                                   int n0, int n1, int n2, int n3) {
  int i = (blockIdx.x * 256 + threadIdx.x) * 4;
  const float* s;
  bf16* d;
  int off;
  if (i < n0) { s = s0; d = d0; off = i; }
  else if (i < n0 + n1) { s = s1; d = d1; off = i - n0; }
  else if (i < n0 + n1 + n2) { s = s2; d = d2; off = i - n0 - n1; }
  else if (i < n0 + n1 + n2 + n3) { s = s3; d = d3; off = i - n0 - n1 - n2; }
  else return;
  float4 v = *(const float4*)(s + off);
  d[off + 0] = (bf16)v.x;
  d[off + 1] = (bf16)v.y;
  d[off + 2] = (bf16)v.z;
  d[off + 3] = (bf16)v.w;
}

// ---------------- LayerNorm fp32-in -> bf16 out, row = 1024 ----------------
__global__ __launch_bounds__(256) void ln_kernel(const float* __restrict__ in,
                                                 const float* __restrict__ g,
                                                 const float* __restrict__ b,
                                                 bf16* __restrict__ out) {
  const int row = blockIdx.x;
  const int tid = threadIdx.x;
  float4 v = ((const float4*)(in + (size_t)row * 1024))[tid];
  float s = v.x + v.y + v.z + v.w;
  float s2 = v.x * v.x + v.y * v.y + v.z * v.z + v.w * v.w;
#pragma unroll
  for (int off = 1; off < 64; off <<= 1) {
    s += __shfl_xor(s, off);
    s2 += __shfl_xor(s2, off);
  }
  __shared__ float red[8];
  int w = tid >> 6, lane = tid & 63;
  if (lane == 0) { red[w] = s; red[4 + w] = s2; }
  __syncthreads();
  s = red[0] + red[1] + red[2] + red[3];
  s2 = red[4] + red[5] + red[6] + red[7];
  const float mean = s * (1.f / 1024.f);
  const float var = s2 * (1.f / 1024.f) - mean * mean;
  const float rstd = rsqrtf(var + 1e-5f);
  float4 gv = ((const float4*)g)[tid];
  float4 bv = ((const float4*)b)[tid];
  bf16* orow = out + (size_t)row * 1024 + tid * 4;
  orow[0] = (bf16)((v.x - mean) * rstd * gv.x + bv.x);
  orow[1] = (bf16)((v.y - mean) * rstd * gv.y + bv.y);
  orow[2] = (bf16)((v.z - mean) * rstd * gv.z + bv.z);
  orow[3] = (bf16)((v.w - mean) * rstd * gv.w + bv.w);
}

// ---------------- LayerNorm bf16-in -> bf16 out, row = 1024 ----------------
__global__ __launch_bounds__(256) void ln_kernel_b(const bf16* __restrict__ in,
                                                   const float* __restrict__ g,
                                                   const float* __restrict__ b,
                                                   bf16* __restrict__ out) {
  const int row = blockIdx.x;
  const int tid = threadIdx.x;
  bf16x4 vb = ((const bf16x4*)(in + (size_t)row * 1024))[tid];
  float4 v;
  v.x = (float)vb[0]; v.y = (float)vb[1]; v.z = (float)vb[2]; v.w = (float)vb[3];
  float s = v.x + v.y + v.z + v.w;
  float s2 = v.x * v.x + v.y * v.y + v.z * v.z + v.w * v.w;
#pragma unroll
  for (int off = 1; off < 64; off <<= 1) {
    s += __shfl_xor(s, off);
    s2 += __shfl_xor(s2, off);
  }
  __shared__ float red[8];
  int w = tid >> 6, lane = tid & 63;
  if (lane == 0) { red[w] = s; red[4 + w] = s2; }
  __syncthreads();
  s = red[0] + red[1] + red[2] + red[3];
  s2 = red[4] + red[5] + red[6] + red[7];
  const float mean = s * (1.f / 1024.f);
  const float var = s2 * (1.f / 1024.f) - mean * mean;
  const float rstd = rsqrtf(var + 1e-5f);
  float4 gv = ((const float4*)g)[tid];
  float4 bv = ((const float4*)b)[tid];
  bf16* orow = out + (size_t)row * 1024 + tid * 4;
  orow[0] = (bf16)((v.x - mean) * rstd * gv.x + bv.x);
  orow[1] = (bf16)((v.y - mean) * rstd * gv.y + bv.y);
  orow[2] = (bf16)((v.z - mean) * rstd * gv.z + bv.z);
  orow[3] = (bf16)((v.w - mean) * rstd * gv.w + bv.w);
}

// ---------------- 256x256 deep-pipelined GEMM: C = A * B^T ----------------
// EPI 0: bf16 out. EPI 1: bias + exact GELU -> bf16.
template <int EPI>
__global__ __launch_bounds__(512, 2) void gemm256(const bf16* __restrict__ A,
                                                  const bf16* __restrict__ B,
                                                  bf16* __restrict__ outb,
                                                  const float* __restrict__ bias,
                                                  int M, int N, int K, int gridN) {
  __shared__ bf16 As[2][256 * 64];
  __shared__ bf16 Bs[2][256 * 64];
  const int nwg = gridDim.x;
  const int bid = blockIdx.x;
  const int swz = (bid & 7) * (nwg >> 3) + (bid >> 3);  // nwg % 8 == 0 (bijective)
  const int bx = swz % gridN, by = swz / gridN;
  const int brow = by * 256, bcol = bx * 256;
  const int tid = threadIdx.x;
  const int lane = tid & 63, wid = tid >> 6;
  const int wm = wid >> 2, wn = wid & 3;
  const int lr = lane & 15, lk4 = lane >> 4;
  const int strow = tid >> 3, stc = tid & 7;
  const int NT = K >> 6;
  f32x4 acc[8][4] = {};

#define STAGE(tt, bb)                                                                   \
  {                                                                                     \
    const int k0_ = (tt)*64;                                                            \
    _Pragma("unroll") for (int s_ = 0; s_ < 4; ++s_) {                                  \
      const int r_ = s_ * 64 + strow;                                                   \
      const int g_ = (stc ^ (strow & 7)) * 8;                                           \
      async16(A + (size_t)(brow + r_) * K + k0_ + g_, &As[bb][r_ * 64 + stc * 8]);      \
      async16(B + (size_t)(bcol + r_) * K + k0_ + g_, &Bs[bb][r_ * 64 + stc * 8]);      \
    }                                                                                   \
  }

  STAGE(0, 0);
  STAGE(1, 1);
  asm volatile("s_waitcnt vmcnt(8)" ::: "memory");
  wg_barrier();

  for (int t = 0; t < NT; ++t) {
    const int cur = t & 1;
    bf16x8 af[8][2], bfr[4][2];
#pragma unroll
    for (int m = 0; m < 8; ++m)
#pragma unroll
      for (int kk = 0; kk < 2; ++kk) {
        const int row = wm * 128 + m * 16 + lr;
        const int kc = kk * 4 + lk4;
        af[m][kk] = *(const bf16x8*)&As[cur][row * 64 + ((kc ^ (row & 7)) * 8)];
      }
#pragma unroll
    for (int n = 0; n < 4; ++n)
#pragma unroll
      for (int kk = 0; kk < 2; ++kk) {
        const int row = wn * 64 + n * 16 + lr;
        const int kc = kk * 4 + lk4;
        bfr[n][kk] = *(const bf16x8*)&Bs[cur][row * 64 + ((kc ^ (row & 7)) * 8)];
      }
    asm volatile("s_waitcnt lgkmcnt(0)" ::: "memory");
    wg_barrier();
    if (t + 2 < NT) STAGE(t + 2, cur);
    __builtin_amdgcn_s_setprio(1);
#pragma unroll
    for (int m = 0; m < 8; ++m)
#pragma unroll
      for (int n = 0; n < 4; ++n) {
        acc[m][n] = __builtin_amdgcn_mfma_f32_16x16x32_bf16(af[m][0], bfr[n][0], acc[m][n], 0, 0, 0);
        acc[m][n] = __builtin_amdgcn_mfma_f32_16x16x32_bf16(af[m][1], bfr[n][1], acc[m][n], 0, 0, 0);
      }
    __builtin_amdgcn_s_setprio(0);
    if (t + 1 < NT) {
      if (t + 2 < NT) {
        asm volatile("s_waitcnt vmcnt(8)" ::: "memory");
      } else {
        asm volatile("s_waitcnt vmcnt(0)" ::: "memory");
      }
      wg_barrier();
    }
  }
#undef STAGE
  const int r0 = brow + wm * 128 + lk4 * 4;
  const int c0 = bcol + wn * 64 + lr;
  float bias_v[4];
  if (EPI == 1) {
#pragma unroll
    for (int n = 0; n < 4; ++n) bias_v[n] = bias[c0 + n * 16];
  }
#pragma unroll
  for (int m = 0; m < 8; ++m)
#pragma unroll
    for (int n = 0; n < 4; ++n)
#pragma unroll
      for (int j = 0; j < 4; ++j) {
        const int r = r0 + m * 16 + j;
        const int c = c0 + n * 16;
        float v = acc[m][n][j];
        if (EPI == 1) {
          v += bias_v[n];
          v = 0.5f * v * (1.0f + erff(v * 0.70710678118654752f));
        }
        outb[(size_t)r * N + c] = (bf16)v;
      }
}

// ---------------- 128x128 GEMM, 8 waves = 2M x 2N x 2K-slices ----------------
// EPI 0 (proj): outb = (bf16)(acc + bias + residf)   [fp32 residual in, bf16 out]
// EPI 1 (FC2):  outf = acc + bias + (float)residb    [bf16 residual in, fp32 out]
template <int EPI>
__global__ __launch_bounds__(512, 2) void gemm128(const bf16* __restrict__ A,
                                                  const bf16* __restrict__ B,
                                                  bf16* __restrict__ outb,
                                                  float* __restrict__ outf,
                                                  const float* __restrict__ bias,
                                                  const float* __restrict__ residf,
                                                  const bf16* __restrict__ residb,
                                                  int M, int N, int K, int gridN) {
  __shared__ bf16 As[2][128 * 64];
  __shared__ bf16 Bs[2][128 * 64];
  const int nwg = gridDim.x;
  const int bid = blockIdx.x;
  const int swz = (bid & 7) * (nwg >> 3) + (bid >> 3);  // nwg % 8 == 0
  const int bx = swz % gridN, by = swz / gridN;
  const int brow = by * 128, bcol = bx * 128;
  const int tid = threadIdx.x;
  const int lane = tid & 63, wid = tid >> 6;
  const int wk = wid & 1, wn = (wid >> 1) & 1, wm = wid >> 2;  // 2K x 2N x 2M
  const int lr = lane & 15, lk4 = lane >> 4;
  const int strow = tid >> 3, stc = tid & 7;
  const int NT = K >> 6;
  f32x4 acc[4][4] = {};

#define STAGE1(tt, bb)                                                                  \
  {                                                                                     \
    const int k0_ = (tt)*64;                                                            \
    _Pragma("unroll") for (int s_ = 0; s_ < 2; ++s_) {                                  \
      const int r_ = s_ * 64 + strow;                                                   \
      const int g_ = (stc ^ (strow & 7)) * 8;                                           \
      async16(A + (size_t)(brow + r_) * K + k0_ + g_, &As[bb][r_ * 64 + stc * 8]);      \
      async16(B + (size_t)(bcol + r_) * K + k0_ + g_, &Bs[bb][r_ * 64 + stc * 8]);      \
    }                                                                                   \
  }

  STAGE1(0, 0);
  STAGE1(1, 1);
  asm volatile("s_waitcnt vmcnt(4)" ::: "memory");
  wg_barrier();

  const int kc = wk * 4 + lk4;  // this wave's K-half
  for (int t = 0; t < NT; ++t) {
    const int cur = t & 1;
    bf16x8 af[4], bfr[4];
#pragma unroll
    for (int m = 0; m < 4; ++m) {
      const int row = wm * 64 + m * 16 + lr;
      af[m] = *(const bf16x8*)&As[cur][row * 64 + ((kc ^ (row & 7)) * 8)];
    }
#pragma unroll
    for (int n = 0; n < 4; ++n) {
      const int row = wn * 64 + n * 16 + lr;
      bfr[n] = *(const bf16x8*)&Bs[cur][row * 64 + ((kc ^ (row & 7)) * 8)];
    }
    asm volatile("s_waitcnt lgkmcnt(0)" ::: "memory");
    wg_barrier();
    if (t + 2 < NT) STAGE1(t + 2, cur);
    __builtin_amdgcn_s_setprio(1);
#pragma unroll
    for (int m = 0; m < 4; ++m)
#pragma unroll
      for (int n = 0; n < 4; ++n)
        acc[m][n] = __builtin_amdgcn_mfma_f32_16x16x32_bf16(af[m], bfr[n], acc[m][n], 0, 0, 0);
    __builtin_amdgcn_s_setprio(0);
    if (t + 1 < NT) {
      if (t + 2 < NT) {
        asm volatile("s_waitcnt vmcnt(4)" ::: "memory");
      } else {
        asm volatile("s_waitcnt vmcnt(0)" ::: "memory");
      }
      wg_barrier();
    }
  }
#undef STAGE1
  // ---- cross-K reduction through LDS (As/Bs now free) ----
  __syncthreads();
  {
    const int r = wm * 2 + wn;
    float* reg = (r < 2) ? ((float*)&As[0][0] + r * 4096)
                         : ((float*)&Bs[0][0] + (r - 2) * 4096);
    if (wk == 1) {
#pragma unroll
      for (int m = 0; m < 4; ++m)
#pragma unroll
        for (int n = 0; n < 4; ++n)
#pragma unroll
          for (int j = 0; j < 4; ++j)
            reg[(m * 16 + n * 4 + j) * 64 + lane] = acc[m][n][j];
    }
    __syncthreads();
    if (wk == 0) {
      const int r0 = brow + wm * 64 + lk4 * 4;
      const int c0 = bcol + wn * 64 + lr;
#pragma unroll
      for (int m = 0; m < 4; ++m)
#pragma unroll
        for (int n = 0; n < 4; ++n) {
          const int c = c0 + n * 16;
          const float bv = bias[c];
#pragma unroll
          for (int j = 0; j < 4; ++j) {
            const int rr = r0 + m * 16 + j;
            float v = acc[m][n][j] + reg[(m * 16 + n * 4 + j) * 64 + lane] + bv;
            if (EPI == 0) {
              outb[(size_t)rr * N + c] = (bf16)(v + residf[(size_t)rr * N + c]);
            } else {
              outf[(size_t)rr * N + c] = v + (float)residb[(size_t)rr * N + c];
            }
          }
        }
    }
  }
}

// ---------------- Flash attention (QBLK=128, 8 waves; unroll-2, hoisted addrs) --------
__global__ __launch_bounds__(512, 4) void flash_kernel(const bf16* __restrict__ qkv,
                                                       bf16* __restrict__ out) {
  const int bid = blockIdx.x;                 // 0..511
  const int swz = (bid & 7) * 64 + (bid >> 3);  // XCD-chunked (512 = 8*64, bijective)
  const int qt = swz & 15;
  const int bh = swz >> 4;
  const int b = bh >> 4, h = bh & 15;
  const int tid = threadIdx.x;
  const int lane = tid & 63, w = tid >> 6;
  const int lr = lane & 15, lk4 = lane >> 4;
  const bf16* Qp = qkv + (size_t)(b * 2048) * 3072 + h * 64;
  const bf16* Kp = Qp + 1024;
  const bf16* Vp = Qp + 2048;
  __shared__ bf16 Ks[2][64 * 64];
  __shared__ bf16 VTs[2][64 * 64];
  __shared__ bf16 Ps[128 * 64 + 4096];  // +8KB pad -> 56KB total LDS
  const int qw0 = qt * 128 + w * 16;
  const float SC = 0.125f * 1.44269504f;
  const float THRU = 8.0f / SC;
  bf16x8 qf[2];
#pragma unroll
  for (int kk = 0; kk < 2; ++kk)
    qf[kk] = *(const bf16x8*)(Qp + (size_t)(qw0 + lr) * 3072 + kk * 32 + lk4 * 8);
  f32x4 o[4] = {};
  float mrun = -1e30f, lrun = 0.f;
  const int sr = tid >> 3, sc8 = tid & 7;
  const int vd = tid & 63, vkc = (tid >> 6) * 8;
  const int vch = tid >> 6;
  const int prow = (w * 16 + lr) * 64;
  int koff[4][2], pw[4], pr[2];
#pragma unroll
  for (int n = 0; n < 4; ++n) {
#pragma unroll
    for (int kk = 0; kk < 2; ++kk)
      koff[n][kk] = (n * 16 + lr) * 64 + (((kk * 4 + lk4) ^ (lr & 7)) * 8);
    pw[n] = prow + (((n * 2 + (lk4 >> 1)) ^ (lr & 7)) * 8) + (lk4 & 1) * 4;
  }
#pragma unroll
  for (int kk = 0; kk < 2; ++kk) pr[kk] = prow + (((kk * 4 + lk4) ^ (lr & 7)) * 8);
  const int kso = sc8 ^ (sr & 7);
  const int kdst = sr * 64 + sc8 * 8;
  const int vdst = vd * 64 + ((vch ^ (vd & 7)) * 8);
  const bf16* Kst = Kp + (size_t)64 * 3072;
  const bf16* Vst = Vp + (size_t)64 * 3072;
  const int ksrc = sr * 3072 + kso * 8;
  const int vsrc = vkc * 3072 + vd;
  bf16 vv[8];
  async16(Kp + ksrc, &Ks[0][kdst]);
#pragma unroll
  for (int j = 0; j < 8; ++j) vv[j] = Vp[vsrc + j * 3072];
  {
    bf16x8 a;
#pragma unroll
    for (int j = 0; j < 8; ++j) a[j] = vv[j];
    *(bf16x8*)&VTs[0][vdst] = a;
  }
  __syncthreads();

#define FTILE(CUR, PREF)                                                                \
  {                                                                                     \
    if (PREF) {                                                                         \
      async16(Kst + ksrc, &Ks[CUR ^ 1][kdst]);                                          \
      _Pragma("unroll") for (int j = 0; j < 8; ++j) vv[j] = Vst[vsrc + j * 3072];       \
    }                                                                                   \
    f32x4 st[4] = {};                                                                   \
    __builtin_amdgcn_s_setprio(1);                                                      \
    _Pragma("unroll") for (int n = 0; n < 4; ++n)                                       \
      _Pragma("unroll") for (int kk = 0; kk < 2; ++kk) {                                \
        bf16x8 kf = *(const bf16x8*)&Ks[CUR][koff[n][kk]];                              \
        st[n] = __builtin_amdgcn_mfma_f32_16x16x32_bf16(kf, qf[kk], st[n], 0, 0, 0);    \
      }                                                                                 \
    __builtin_amdgcn_s_setprio(0);                                                      \
    float m01 = fmaxf(fmaxf(st[0][0], st[0][1]), fmaxf(st[0][2], st[0][3]));            \
    float m23 = fmaxf(fmaxf(st[1][0], st[1][1]), fmaxf(st[1][2], st[1][3]));            \
    float m45 = fmaxf(fmaxf(st[2][0], st[2][1]), fmaxf(st[2][2], st[2][3]));            \
    float m67 = fmaxf(fmaxf(st[3][0], st[3][1]), fmaxf(st[3][2], st[3][3]));            \
    float mx = fmaxf(fmaxf(m01, m23), fmaxf(m45, m67));                                 \
    mx = fmaxf(mx, __shfl_xor(mx, 16));                                                 \
    mx = fmaxf(mx, __shfl_xor(mx, 32));                                                 \
    const bool skip = __all(mx <= mrun + THRU);                                         \
    const float mn = skip ? mrun : fmaxf(mrun, mx);                                     \
    const float mnS = mn * SC;                                                          \
    float rs = 0.f;                                                                     \
    _Pragma("unroll") for (int n = 0; n < 4; ++n) {                                     \
      float p0 = exp2f(fmaf(st[n][0], SC, -mnS));                                       \
      float p1 = exp2f(fmaf(st[n][1], SC, -mnS));                                       \
      float p2 = exp2f(fmaf(st[n][2], SC, -mnS));                                       \
      float p3 = exp2f(fmaf(st[n][3], SC, -mnS));                                       \
      rs += (p0 + p1) + (p2 + p3);                                                      \
      bf16x4 pk;                                                                        \
      pk[0] = (bf16)p0; pk[1] = (bf16)p1; pk[2] = (bf16)p2; pk[3] = (bf16)p3;           \
      *(bf16x4*)&Ps[pw[n]] = pk;                                                        \
    }                                                                                   \
    rs += __shfl_xor(rs, 16);                                                           \
    rs += __shfl_xor(rs, 32);                                                           \
    if (!skip) {                                                                        \
      const float alpha = exp2f(fmaf(mrun, SC, -mnS));                                  \
      lrun = lrun * alpha + rs;                                                         \
      mrun = mn;                                                                        \
      _Pragma("unroll") for (int c = 0; c < 4; ++c)                                     \
        _Pragma("unroll") for (int j = 0; j < 4; ++j) o[c][j] *= alpha;                 \
    } else {                                                                            \
      lrun += rs;                                                                       \
    }                                                                                   \
    bf16x8 pb[2];                                                                       \
    _Pragma("unroll") for (int kk = 0; kk < 2; ++kk)                                    \
      pb[kk] = *(const bf16x8*)&Ps[pr[kk]];                                             \
    __builtin_amdgcn_s_setprio(1);                                                      \
    _Pragma("unroll") for (int c = 0; c < 4; ++c)                                       \
      _Pragma("unroll") for (int kk = 0; kk < 2; ++kk) {                                \
        bf16x8 vfr = *(const bf16x8*)&VTs[CUR][koff[c][kk]];                            \
        o[c] = __builtin_amdgcn_mfma_f32_16x16x32_bf16(vfr, pb[kk], o[c], 0, 0, 0);     \
      }                                                                                 \
    __builtin_amdgcn_s_setprio(0);                                                      \
    if (PREF) {                                                                         \
      bf16x8 a;                                                                         \
      _Pragma("unroll") for (int j = 0; j < 8; ++j) a[j] = vv[j];                       \
      *(bf16x8*)&VTs[CUR ^ 1][vdst] = a;                                                \
      Kst += (size_t)64 * 3072;                                                         \
      Vst += (size_t)64 * 3072;                                                         \
    }                                                                                   \
    __syncthreads();                                                                    \
  }

  for (int tt = 0; tt < 16; ++tt) {
    FTILE(0, true);
    FTILE(1, (tt < 15));
  }
#undef FTILE

  const float inv = 1.f / lrun;
#pragma unroll
  for (int c = 0; c < 4; ++c) {
    bf16x4 ov;
#pragma unroll
    for (int j = 0; j < 4; ++j) ov[j] = (bf16)(o[c][j] * inv);
    *(bf16x4*)&out[(size_t)(b * 2048 + qw0 + lr) * 1024 + h * 64 + c * 16 + lk4 * 4] = ov;
  }
}

// ---------------- launch ----------------
extern "C" void kernel_launch(void* const* d_in, const int* in_sizes, int n_in,
                              void* d_out, int out_size, void* d_ws, size_t ws_size,
                              hipStream_t stream) {
  const float* x      = (const float*)d_in[0];
  const float* w_qkv  = (const float*)d_in[1];
  const float* w_proj = (const float*)d_in[2];
  const float* b_proj = (const float*)d_in[3];
  const float* ln1_g  = (const float*)d_in[4];
  const float* ln1_b  = (const float*)d_in[5];
  const float* ln2_g  = (const float*)d_in[6];
  const float* ln2_b  = (const float*)d_in[7];
  const float* w_fc1  = (const float*)d_in[8];
  const float* b_fc1  = (const float*)d_in[9];
  const float* w_fc2  = (const float*)d_in[10];
  const float* b_fc2  = (const float*)d_in[11];

  char* W = (char*)d_ws;
  bf16* wqkvb = (bf16*)(W + 0);                    //  6,291,456
  bf16* wprojb = (bf16*)(W + 6291456);             //  2,097,152
  bf16* wfc1b = (bf16*)(W + 8388608);              //  8,388,608
  bf16* wfc2b = (bf16*)(W + 16777216);             //  8,388,608
  bf16* xn    = (bf16*)(W + 25165824);             //  8,388,608
  bf16* qkvb  = (bf16*)(W + 33554432);             // 25,165,824
  bf16* attnb = (bf16*)(W + 58720256);             //  8,388,608
  bf16* x2b   = (bf16*)(W + 67108864);             //  8,388,608
  bf16* hbuf  = (bf16*)(W + 83886080);             // 33,554,432
  float* outf = (float*)d_out;

  f2b4_kernel<<<12288, 256, 0, stream>>>(w_qkv, w_proj, w_fc1, w_fc2,
                                         wqkvb, wprojb, wfc1b, wfc2b,
                                         3145728, 1048576, 4194304, 4194304);

  // LN1
  ln_kernel<<<4096, 256, 0, stream>>>(x, ln1_g, ln1_b, xn);
  // QKV GEMM (256² deep-pipeline, grid 12x16=192)
  gemm256<0><<<192, 512, 0, stream>>>(xn, wqkvb, qkvb, nullptr, 4096, 3072, 1024, 12);
  // attention (QBLK=128, 8 waves, XCD-chunked 1-D grid)
  flash_kernel<<<512, 512, 0, stream>>>(qkvb, attnb);
  // proj + bias + residual(x fp32) -> x2b bf16 (128² split-K, grid 32x8=256)
  gemm128<0><<<256, 512, 0, stream>>>(attnb, wprojb, x2b, nullptr, b_proj, x, nullptr,
                                      4096, 1024, 1024, 8);
  // LN2 (bf16 in)
  ln_kernel_b<<<4096, 256, 0, stream>>>(x2b, ln2_g, ln2_b, xn);
  // FC1 + bias + GELU (256² deep-pipeline, grid 16x16=256)
  gemm256<1><<<256, 512, 0, stream>>>(xn, wfc1b, hbuf, b_fc1, 4096, 4096, 1024, 16);
  // FC2 + bias + residual(x2b bf16) -> out fp32 (128² split-K, grid 32x8=256)
  gemm128<1><<<256, 512, 0, stream>>>(hbuf, wfc2b, nullptr, outf, b_fc2, nullptr, x2b,
                                      4096, 1024, 4096, 8);
}

// Round 17
// 236.589 us; speedup vs baseline: 1.0383x; 1.0383x over previous
//
#include <hip/hip_runtime.h>
#include <hip/hip_bf16.h>
#include <math.h>

typedef __bf16 bf16;
typedef __attribute__((ext_vector_type(8))) __bf16 bf16x8;
typedef __attribute__((ext_vector_type(4))) __bf16 bf16x4;
typedef __attribute__((ext_vector_type(4))) float f32x4;

#define DEV static __device__ __forceinline__

typedef const void __attribute__((address_space(1)))* gptr_t;
typedef void __attribute__((address_space(3)))* lptr_t;

DEV void async16(const void* g, void* l) {
  __builtin_amdgcn_global_load_lds((gptr_t)g, (lptr_t)l, 16, 0, 0);
}

DEV void wg_barrier() {
  __builtin_amdgcn_sched_barrier(0);
  __builtin_amdgcn_s_barrier();
  __builtin_amdgcn_sched_barrier(0);
}

// tanh-form GELU: v * t/(t+1), t = exp(2u), u = 0.79788456*(v + 0.044715 v^3)
DEV float gelu_fast(float v) {
  float u = 0.7978845608f * (v + 0.044715f * v * v * v);
  float t = exp2f(u * 2.8853900817779268f);
  float r = __builtin_amdgcn_rcpf(t + 1.0f);
  return v * t * r;
}

// ---------------- fused fp32 -> bf16 convert (4 weight arrays) ----------------
__global__ __launch_bounds__(256) void f2b4_kernel(const float* __restrict__ s0,
                                                   const float* __restrict__ s1,
                                                   const float* __restrict__ s2,
                                                   const float* __restrict__ s3,
                                                   bf16* __restrict__ d0, bf16* __restrict__ d1,
                                                   bf16* __restrict__ d2, bf16* __restrict__ d3,
                                                   int n0, int n1, int n2, int n3) {
  int i = (blockIdx.x * 256 + threadIdx.x) * 4;
  const float* s;
  bf16* d;
  int off;
  if (i < n0) { s = s0; d = d0; off = i; }
  else if (i < n0 + n1) { s = s1; d = d1; off = i - n0; }
  else if (i < n0 + n1 + n2) { s = s2; d = d2; off = i - n0 - n1; }
  else if (i < n0 + n1 + n2 + n3) { s = s3; d = d3; off = i - n0 - n1 - n2; }
  else return;
  float4 v = *(const float4*)(s + off);
  bf16x4 pk;
  pk[0] = (bf16)v.x; pk[1] = (bf16)v.y; pk[2] = (bf16)v.z; pk[3] = (bf16)v.w;
  *(bf16x4*)(d + off) = pk;
}

// ---------------- LayerNorm fp32-in -> bf16 out, row = 1024 ----------------
__global__ __launch_bounds__(256) void ln_kernel(const float* __restrict__ in,
                                                 const float* __restrict__ g,
                                                 const float* __restrict__ b,
                                                 bf16* __restrict__ out) {
  const int row = blockIdx.x;
  const int tid = threadIdx.x;
  float4 v = ((const float4*)(in + (size_t)row * 1024))[tid];
  float s = v.x + v.y + v.z + v.w;
  float s2 = v.x * v.x + v.y * v.y + v.z * v.z + v.w * v.w;
#pragma unroll
  for (int off = 1; off < 64; off <<= 1) {
    s += __shfl_xor(s, off);
    s2 += __shfl_xor(s2, off);
  }
  __shared__ float red[8];
  int w = tid >> 6, lane = tid & 63;
  if (lane == 0) { red[w] = s; red[4 + w] = s2; }
  __syncthreads();
  s = red[0] + red[1] + red[2] + red[3];
  s2 = red[4] + red[5] + red[6] + red[7];
  const float mean = s * (1.f / 1024.f);
  const float var = s2 * (1.f / 1024.f) - mean * mean;
  const float rstd = rsqrtf(var + 1e-5f);
  float4 gv = ((const float4*)g)[tid];
  float4 bv = ((const float4*)b)[tid];
  bf16x4 pk;
  pk[0] = (bf16)((v.x - mean) * rstd * gv.x + bv.x);
  pk[1] = (bf16)((v.y - mean) * rstd * gv.y + bv.y);
  pk[2] = (bf16)((v.z - mean) * rstd * gv.z + bv.z);
  pk[3] = (bf16)((v.w - mean) * rstd * gv.w + bv.w);
  *(bf16x4*)(out + (size_t)row * 1024 + tid * 4) = pk;
}

// ---------------- LayerNorm bf16-in -> bf16 out, row = 1024 ----------------
__global__ __launch_bounds__(256) void ln_kernel_b(const bf16* __restrict__ in,
                                                   const float* __restrict__ g,
                                                   const float* __restrict__ b,
                                                   bf16* __restrict__ out) {
  const int row = blockIdx.x;
  const int tid = threadIdx.x;
  bf16x4 vb = ((const bf16x4*)(in + (size_t)row * 1024))[tid];
  float4 v;
  v.x = (float)vb[0]; v.y = (float)vb[1]; v.z = (float)vb[2]; v.w = (float)vb[3];
  float s = v.x + v.y + v.z + v.w;
  float s2 = v.x * v.x + v.y * v.y + v.z * v.z + v.w * v.w;
#pragma unroll
  for (int off = 1; off < 64; off <<= 1) {
    s += __shfl_xor(s, off);
    s2 += __shfl_xor(s2, off);
  }
  __shared__ float red[8];
  int w = tid >> 6, lane = tid & 63;
  if (lane == 0) { red[w] = s; red[4 + w] = s2; }
  __syncthreads();
  s = red[0] + red[1] + red[2] + red[3];
  s2 = red[4] + red[5] + red[6] + red[7];
  const float mean = s * (1.f / 1024.f);
  const float var = s2 * (1.f / 1024.f) - mean * mean;
  const float rstd = rsqrtf(var + 1e-5f);
  float4 gv = ((const float4*)g)[tid];
  float4 bv = ((const float4*)b)[tid];
  bf16x4 pk;
  pk[0] = (bf16)((v.x - mean) * rstd * gv.x + bv.x);
  pk[1] = (bf16)((v.y - mean) * rstd * gv.y + bv.y);
  pk[2] = (bf16)((v.z - mean) * rstd * gv.z + bv.z);
  pk[3] = (bf16)((v.w - mean) * rstd * gv.w + bv.w);
  *(bf16x4*)(out + (size_t)row * 1024 + tid * 4) = pk;
}

// ---------------- 256x256 deep-pipelined GEMM: C = A * B^T ----------------
// EPI 0: bf16 out. EPI 1: bias + GELU (tanh-form) -> bf16.
template <int EPI>
__global__ __launch_bounds__(512, 2) void gemm256(const bf16* __restrict__ A,
                                                  const bf16* __restrict__ B,
                                                  bf16* __restrict__ outb,
                                                  const float* __restrict__ bias,
                                                  int M, int N, int K, int gridN) {
  __shared__ bf16 As[2][256 * 64];
  __shared__ bf16 Bs[2][256 * 64];
  const int nwg = gridDim.x;
  const int bid = blockIdx.x;
  const int swz = (bid & 7) * (nwg >> 3) + (bid >> 3);  // nwg % 8 == 0 (bijective)
  const int bx = swz % gridN, by = swz / gridN;
  const int brow = by * 256, bcol = bx * 256;
  const int tid = threadIdx.x;
  const int lane = tid & 63, wid = tid >> 6;
  const int wm = wid >> 2, wn = wid & 3;
  const int lr = lane & 15, lk4 = lane >> 4;
  const int strow = tid >> 3, stc = tid & 7;
  const int NT = K >> 6;
  f32x4 acc[8][4] = {};

#define STAGE(tt, bb)                                                                   \
  {                                                                                     \
    const int k0_ = (tt)*64;                                                            \
    _Pragma("unroll") for (int s_ = 0; s_ < 4; ++s_) {                                  \
      const int r_ = s_ * 64 + strow;                                                   \
      const int g_ = (stc ^ (strow & 7)) * 8;                                           \
      async16(A + (size_t)(brow + r_) * K + k0_ + g_, &As[bb][r_ * 64 + stc * 8]);      \
      async16(B + (size_t)(bcol + r_) * K + k0_ + g_, &Bs[bb][r_ * 64 + stc * 8]);      \
    }                                                                                   \
  }

  STAGE(0, 0);
  STAGE(1, 1);
  asm volatile("s_waitcnt vmcnt(8)" ::: "memory");
  wg_barrier();

  for (int t = 0; t < NT; ++t) {
    const int cur = t & 1;
    bf16x8 af[8][2], bfr[4][2];
#pragma unroll
    for (int m = 0; m < 8; ++m)
#pragma unroll
      for (int kk = 0; kk < 2; ++kk) {
        const int row = wm * 128 + m * 16 + lr;
        const int kc = kk * 4 + lk4;
        af[m][kk] = *(const bf16x8*)&As[cur][row * 64 + ((kc ^ (row & 7)) * 8)];
      }
#pragma unroll
    for (int n = 0; n < 4; ++n)
#pragma unroll
      for (int kk = 0; kk < 2; ++kk) {
        const int row = wn * 64 + n * 16 + lr;
        const int kc = kk * 4 + lk4;
        bfr[n][kk] = *(const bf16x8*)&Bs[cur][row * 64 + ((kc ^ (row & 7)) * 8)];
      }
    asm volatile("s_waitcnt lgkmcnt(0)" ::: "memory");
    wg_barrier();
    if (t + 2 < NT) STAGE(t + 2, cur);
    __builtin_amdgcn_s_setprio(1);
#pragma unroll
    for (int m = 0; m < 8; ++m)
#pragma unroll
      for (int n = 0; n < 4; ++n) {
        acc[m][n] = __builtin_amdgcn_mfma_f32_16x16x32_bf16(af[m][0], bfr[n][0], acc[m][n], 0, 0, 0);
        acc[m][n] = __builtin_amdgcn_mfma_f32_16x16x32_bf16(af[m][1], bfr[n][1], acc[m][n], 0, 0, 0);
      }
    __builtin_amdgcn_s_setprio(0);
    if (t + 1 < NT) {
      if (t + 2 < NT) {
        asm volatile("s_waitcnt vmcnt(8)" ::: "memory");
      } else {
        asm volatile("s_waitcnt vmcnt(0)" ::: "memory");
      }
      wg_barrier();
    }
  }
#undef STAGE
  const int r0 = brow + wm * 128 + lk4 * 4;
  const int c0 = bcol + wn * 64 + lr;
  float bias_v[4];
  if (EPI == 1) {
#pragma unroll
    for (int n = 0; n < 4; ++n) bias_v[n] = bias[c0 + n * 16];
  }
#pragma unroll
  for (int m = 0; m < 8; ++m)
#pragma unroll
    for (int n = 0; n < 4; ++n)
#pragma unroll
      for (int j = 0; j < 4; ++j) {
        const int r = r0 + m * 16 + j;
        const int c = c0 + n * 16;
        float v = acc[m][n][j];
        if (EPI == 1) {
          v = gelu_fast(v + bias_v[n]);
        }
        outb[(size_t)r * N + c] = (bf16)v;
      }
}

// ---------------- 128x128 GEMM, 8 waves = 2M x 2N x 2K-slices ----------------
// EPI 0 (proj): outb = (bf16)(acc + bias + residf)   [fp32 residual in, bf16 out]
// EPI 1 (FC2):  outf = acc + bias + (float)residb    [bf16 residual in, fp32 out]
template <int EPI>
__global__ __launch_bounds__(512, 2) void gemm128(const bf16* __restrict__ A,
                                                  const bf16* __restrict__ B,
                                                  bf16* __restrict__ outb,
                                                  float* __restrict__ outf,
                                                  const float* __restrict__ bias,
                                                  const float* __restrict__ residf,
                                                  const bf16* __restrict__ residb,
                                                  int M, int N, int K, int gridN) {
  __shared__ bf16 As[2][128 * 64];
  __shared__ bf16 Bs[2][128 * 64];
  const int nwg = gridDim.x;
  const int bid = blockIdx.x;
  const int swz = (bid & 7) * (nwg >> 3) + (bid >> 3);  // nwg % 8 == 0
  const int bx = swz % gridN, by = swz / gridN;
  const int brow = by * 128, bcol = bx * 128;
  const int tid = threadIdx.x;
  const int lane = tid & 63, wid = tid >> 6;
  const int wk = wid & 1, wn = (wid >> 1) & 1, wm = wid >> 2;  // 2K x 2N x 2M
  const int lr = lane & 15, lk4 = lane >> 4;
  const int strow = tid >> 3, stc = tid & 7;
  const int NT = K >> 6;
  f32x4 acc[4][4] = {};

#define STAGE1(tt, bb)                                                                  \
  {                                                                                     \
    const int k0_ = (tt)*64;                                                            \
    _Pragma("unroll") for (int s_ = 0; s_ < 2; ++s_) {                                  \
      const int r_ = s_ * 64 + strow;                                                   \
      const int g_ = (stc ^ (strow & 7)) * 8;                                           \
      async16(A + (size_t)(brow + r_) * K + k0_ + g_, &As[bb][r_ * 64 + stc * 8]);      \
      async16(B + (size_t)(bcol + r_) * K + k0_ + g_, &Bs[bb][r_ * 64 + stc * 8]);      \
    }                                                                                   \
  }

  STAGE1(0, 0);
  STAGE1(1, 1);
  asm volatile("s_waitcnt vmcnt(4)" ::: "memory");
  wg_barrier();

  const int kc = wk * 4 + lk4;  // this wave's K-half
  for (int t = 0; t < NT; ++t) {
    const int cur = t & 1;
    bf16x8 af[4], bfr[4];
#pragma unroll
    for (int m = 0; m < 4; ++m) {
      const int row = wm * 64 + m * 16 + lr;
      af[m] = *(const bf16x8*)&As[cur][row * 64 + ((kc ^ (row & 7)) * 8)];
    }
#pragma unroll
    for (int n = 0; n < 4; ++n) {
      const int row = wn * 64 + n * 16 + lr;
      bfr[n] = *(const bf16x8*)&Bs[cur][row * 64 + ((kc ^ (row & 7)) * 8)];
    }
    asm volatile("s_waitcnt lgkmcnt(0)" ::: "memory");
    wg_barrier();
    if (t + 2 < NT) STAGE1(t + 2, cur);
    __builtin_amdgcn_s_setprio(1);
#pragma unroll
    for (int m = 0; m < 4; ++m)
#pragma unroll
      for (int n = 0; n < 4; ++n)
        acc[m][n] = __builtin_amdgcn_mfma_f32_16x16x32_bf16(af[m], bfr[n], acc[m][n], 0, 0, 0);
    __builtin_amdgcn_s_setprio(0);
    if (t + 1 < NT) {
      if (t + 2 < NT) {
        asm volatile("s_waitcnt vmcnt(4)" ::: "memory");
      } else {
        asm volatile("s_waitcnt vmcnt(0)" ::: "memory");
      }
      wg_barrier();
    }
  }
#undef STAGE1
  // ---- cross-K reduction through LDS (As/Bs now free) ----
  __syncthreads();
  {
    const int r = wm * 2 + wn;
    float* reg = (r < 2) ? ((float*)&As[0][0] + r * 4096)
                         : ((float*)&Bs[0][0] + (r - 2) * 4096);
    if (wk == 1) {
#pragma unroll
      for (int m = 0; m < 4; ++m)
#pragma unroll
        for (int n = 0; n < 4; ++n)
#pragma unroll
          for (int j = 0; j < 4; ++j)
            reg[(m * 16 + n * 4 + j) * 64 + lane] = acc[m][n][j];
    }
    __syncthreads();
    if (wk == 0) {
      const int r0 = brow + wm * 64 + lk4 * 4;
      const int c0 = bcol + wn * 64 + lr;
#pragma unroll
      for (int m = 0; m < 4; ++m)
#pragma unroll
        for (int n = 0; n < 4; ++n) {
          const int c = c0 + n * 16;
          const float bv = bias[c];
#pragma unroll
          for (int j = 0; j < 4; ++j) {
            const int rr = r0 + m * 16 + j;
            float v = acc[m][n][j] + reg[(m * 16 + n * 4 + j) * 64 + lane] + bv;
            if (EPI == 0) {
              outb[(size_t)rr * N + c] = (bf16)(v + residf[(size_t)rr * N + c]);
            } else {
              outf[(size_t)rr * N + c] = v + (float)residb[(size_t)rr * N + c];
            }
          }
        }
    }
  }
}

// ---------------- Flash attention (QBLK=128, 8 waves; unroll-2, hoisted addrs) --------
__global__ __launch_bounds__(512, 4) void flash_kernel(const bf16* __restrict__ qkv,
                                                       bf16* __restrict__ out) {
  const int bid = blockIdx.x;                 // 0..511
  const int swz = (bid & 7) * 64 + (bid >> 3);  // XCD-chunked (512 = 8*64, bijective)
  const int qt = swz & 15;
  const int bh = swz >> 4;
  const int b = bh >> 4, h = bh & 15;
  const int tid = threadIdx.x;
  const int lane = tid & 63, w = tid >> 6;
  const int lr = lane & 15, lk4 = lane >> 4;
  const bf16* Qp = qkv + (size_t)(b * 2048) * 3072 + h * 64;
  const bf16* Kp = Qp + 1024;
  const bf16* Vp = Qp + 2048;
  __shared__ bf16 Ks[2][64 * 64];
  __shared__ bf16 VTs[2][64 * 64];
  __shared__ bf16 Ps[128 * 64 + 4096];  // +8KB pad -> 56KB total LDS
  const int qw0 = qt * 128 + w * 16;
  const float SC = 0.125f * 1.44269504f;
  const float THRU = 8.0f / SC;
  bf16x8 qf[2];
#pragma unroll
  for (int kk = 0; kk < 2; ++kk)
    qf[kk] = *(const bf16x8*)(Qp + (size_t)(qw0 + lr) * 3072 + kk * 32 + lk4 * 8);
  f32x4 o[4] = {};
  float mrun = -1e30f, lrun = 0.f;
  const int sr = tid >> 3, sc8 = tid & 7;
  const int vd = tid & 63, vkc = (tid >> 6) * 8;
  const int vch = tid >> 6;
  const int prow = (w * 16 + lr) * 64;
  int koff[4][2], pw[4], pr[2];
#pragma unroll
  for (int n = 0; n < 4; ++n) {
#pragma unroll
    for (int kk = 0; kk < 2; ++kk)
      koff[n][kk] = (n * 16 + lr) * 64 + (((kk * 4 + lk4) ^ (lr & 7)) * 8);
    pw[n] = prow + (((n * 2 + (lk4 >> 1)) ^ (lr & 7)) * 8) + (lk4 & 1) * 4;
  }
#pragma unroll
  for (int kk = 0; kk < 2; ++kk) pr[kk] = prow + (((kk * 4 + lk4) ^ (lr & 7)) * 8);
  const int kso = sc8 ^ (sr & 7);
  const int kdst = sr * 64 + sc8 * 8;
  const int vdst = vd * 64 + ((vch ^ (vd & 7)) * 8);
  const bf16* Kst = Kp + (size_t)64 * 3072;
  const bf16* Vst = Vp + (size_t)64 * 3072;
  const int ksrc = sr * 3072 + kso * 8;
  const int vsrc = vkc * 3072 + vd;
  bf16 vv[8];
  async16(Kp + ksrc, &Ks[0][kdst]);
#pragma unroll
  for (int j = 0; j < 8; ++j) vv[j] = Vp[vsrc + j * 3072];
  {
    bf16x8 a;
#pragma unroll
    for (int j = 0; j < 8; ++j) a[j] = vv[j];
    *(bf16x8*)&VTs[0][vdst] = a;
  }
  __syncthreads();

#define FTILE(CUR, PREF)                                                                \
  {                                                                                     \
    if (PREF) {                                                                         \
      async16(Kst + ksrc, &Ks[CUR ^ 1][kdst]);                                          \
      _Pragma("unroll") for (int j = 0; j < 8; ++j) vv[j] = Vst[vsrc + j * 3072];       \
    }                                                                                   \
    f32x4 st[4] = {};                                                                   \
    __builtin_amdgcn_s_setprio(1);                                                      \
    _Pragma("unroll") for (int n = 0; n < 4; ++n)                                       \
      _Pragma("unroll") for (int kk = 0; kk < 2; ++kk) {                                \
        bf16x8 kf = *(const bf16x8*)&Ks[CUR][koff[n][kk]];                              \
        st[n] = __builtin_amdgcn_mfma_f32_16x16x32_bf16(kf, qf[kk], st[n], 0, 0, 0);    \
      }                                                                                 \
    __builtin_amdgcn_s_setprio(0);                                                      \
    float m01 = fmaxf(fmaxf(st[0][0], st[0][1]), fmaxf(st[0][2], st[0][3]));            \
    float m23 = fmaxf(fmaxf(st[1][0], st[1][1]), fmaxf(st[1][2], st[1][3]));            \
    float m45 = fmaxf(fmaxf(st[2][0], st[2][1]), fmaxf(st[2][2], st[2][3]));            \
    float m67 = fmaxf(fmaxf(st[3][0], st[3][1]), fmaxf(st[3][2], st[3][3]));            \
    float mx = fmaxf(fmaxf(m01, m23), fmaxf(m45, m67));                                 \
    mx = fmaxf(mx, __shfl_xor(mx, 16));                                                 \
    mx = fmaxf(mx, __shfl_xor(mx, 32));                                                 \
    const bool skip = __all(mx <= mrun + THRU);                                         \
    const float mn = skip ? mrun : fmaxf(mrun, mx);                                     \
    const float mnS = mn * SC;                                                          \
    float rs = 0.f;                                                                     \
    _Pragma("unroll") for (int n = 0; n < 4; ++n) {                                     \
      float p0 = exp2f(fmaf(st[n][0], SC, -mnS));                                       \
      float p1 = exp2f(fmaf(st[n][1], SC, -mnS));                                       \
      float p2 = exp2f(fmaf(st[n][2], SC, -mnS));                                       \
      float p3 = exp2f(fmaf(st[n][3], SC, -mnS));                                       \
      rs += (p0 + p1) + (p2 + p3);                                                      \
      bf16x4 pk;                                                                        \
      pk[0] = (bf16)p0; pk[1] = (bf16)p1; pk[2] = (bf16)p2; pk[3] = (bf16)p3;           \
      *(bf16x4*)&Ps[pw[n]] = pk;                                                        \
    }                                                                                   \
    rs += __shfl_xor(rs, 16);                                                           \
    rs += __shfl_xor(rs, 32);                                                           \
    if (!skip) {                                                                        \
      const float alpha = exp2f(fmaf(mrun, SC, -mnS));                                  \
      lrun = lrun * alpha + rs;                                                         \
      mrun = mn;                                                                        \
      _Pragma("unroll") for (int c = 0; c < 4; ++c)                                     \
        _Pragma("unroll") for (int j = 0; j < 4; ++j) o[c][j] *= alpha;                 \
    } else {                                                                            \
      lrun += rs;                                                                       \
    }                                                                                   \
    bf16x8 pb[2];                                                                       \
    _Pragma("unroll") for (int kk = 0; kk < 2; ++kk)                                    \
      pb[kk] = *(const bf16x8*)&Ps[pr[kk]];                                             \
    __builtin_amdgcn_s_setprio(1);                                                      \
    _Pragma("unroll") for (int c = 0; c < 4; ++c)                                       \
      _Pragma("unroll") for (int kk = 0; kk < 2; ++kk) {                                \
        bf16x8 vfr = *(const bf16x8*)&VTs[CUR][koff[c][kk]];                            \
        o[c] = __builtin_amdgcn_mfma_f32_16x16x32_bf16(vfr, pb[kk], o[c], 0, 0, 0);     \
      }                                                                                 \
    __builtin_amdgcn_s_setprio(0);                                                      \
    if (PREF) {                                                                         \
      bf16x8 a;                                                                         \
      _Pragma("unroll") for (int j = 0; j < 8; ++j) a[j] = vv[j];                       \
      *(bf16x8*)&VTs[CUR ^ 1][vdst] = a;                                                \
      Kst += (size_t)64 * 3072;                                                         \
      Vst += (size_t)64 * 3072;                                                         \
    }                                                                                   \
    __syncthreads();                                                                    \
  }

  for (int tt = 0; tt < 16; ++tt) {
    FTILE(0, true);
    FTILE(1, (tt < 15));
  }
#undef FTILE

  const float inv = 1.f / lrun;
#pragma unroll
  for (int c = 0; c < 4; ++c) {
    bf16x4 ov;
#pragma unroll
    for (int j = 0; j < 4; ++j) ov[j] = (bf16)(o[c][j] * inv);
    *(bf16x4*)&out[(size_t)(b * 2048 + qw0 + lr) * 1024 + h * 64 + c * 16 + lk4 * 4] = ov;
  }
}

// ---------------- launch ----------------
extern "C" void kernel_launch(void* const* d_in, const int* in_sizes, int n_in,
                              void* d_out, int out_size, void* d_ws, size_t ws_size,
                              hipStream_t stream) {
  const float* x      = (const float*)d_in[0];
  const float* w_qkv  = (const float*)d_in[1];
  const float* w_proj = (const float*)d_in[2];
  const float* b_proj = (const float*)d_in[3];
  const float* ln1_g  = (const float*)d_in[4];
  const float* ln1_b  = (const float*)d_in[5];
  const float* ln2_g  = (const float*)d_in[6];
  const float* ln2_b  = (const float*)d_in[7];
  const float* w_fc1  = (const float*)d_in[8];
  const float* b_fc1  = (const float*)d_in[9];
  const float* w_fc2  = (const float*)d_in[10];
  const float* b_fc2  = (const float*)d_in[11];

  char* W = (char*)d_ws;
  bf16* wqkvb = (bf16*)(W + 0);                    //  6,291,456
  bf16* wprojb = (bf16*)(W + 6291456);             //  2,097,152
  bf16* wfc1b = (bf16*)(W + 8388608);              //  8,388,608
  bf16* wfc2b = (bf16*)(W + 16777216);             //  8,388,608
  bf16* xn    = (bf16*)(W + 25165824);             //  8,388,608
  bf16* qkvb  = (bf16*)(W + 33554432);             // 25,165,824
  bf16* attnb = (bf16*)(W + 58720256);             //  8,388,608
  bf16* x2b   = (bf16*)(W + 67108864);             //  8,388,608
  bf16* hbuf  = (bf16*)(W + 83886080);             // 33,554,432
  float* outf = (float*)d_out;

  f2b4_kernel<<<12288, 256, 0, stream>>>(w_qkv, w_proj, w_fc1, w_fc2,
                                         wqkvb, wprojb, wfc1b, wfc2b,
                                         3145728, 1048576, 4194304, 4194304);

  // LN1
  ln_kernel<<<4096, 256, 0, stream>>>(x, ln1_g, ln1_b, xn);
  // QKV GEMM (256² deep-pipeline, grid 12x16=192)
  gemm256<0><<<192, 512, 0, stream>>>(xn, wqkvb, qkvb, nullptr, 4096, 3072, 1024, 12);
  // attention (QBLK=128, 8 waves, XCD-chunked 1-D grid)
  flash_kernel<<<512, 512, 0, stream>>>(qkvb, attnb);
  // proj + bias + residual(x fp32) -> x2b bf16 (128² split-K, grid 32x8=256)
  gemm128<0><<<256, 512, 0, stream>>>(attnb, wprojb, x2b, nullptr, b_proj, x, nullptr,
                                      4096, 1024, 1024, 8);
  // LN2 (bf16 in)
  ln_kernel_b<<<4096, 256, 0, stream>>>(x2b, ln2_g, ln2_b, xn);
  // FC1 + bias + GELU (256² deep-pipeline, grid 16x16=256)
  gemm256<1><<<256, 512, 0, stream>>>(xn, wfc1b, hbuf, b_fc1, 4096, 4096, 1024, 16);
  // FC2 + bias + residual(x2b bf16) -> out fp32 (128² split-K, grid 32x8=256)
  gemm128<1><<<256, 512, 0, stream>>>(hbuf, wfc2b, nullptr, outf, b_fc2, nullptr, x2b,
                                      4096, 1024, 4096, 8);
}

// Round 19
// 234.707 us; speedup vs baseline: 1.0466x; 1.0080x over previous
//
#include <hip/hip_runtime.h>
#include <hip/hip_bf16.h>
#include <math.h>

typedef __bf16 bf16;
typedef __attribute__((ext_vector_type(8))) __bf16 bf16x8;
typedef __attribute__((ext_vector_type(4))) __bf16 bf16x4;
typedef __attribute__((ext_vector_type(4))) float f32x4;

#define DEV static __device__ __forceinline__

typedef const void __attribute__((address_space(1)))* gptr_t;
typedef void __attribute__((address_space(3)))* lptr_t;

DEV void async16(const void* g, void* l) {
  __builtin_amdgcn_global_load_lds((gptr_t)g, (lptr_t)l, 16, 0, 0);
}

DEV void wg_barrier() {
  __builtin_amdgcn_sched_barrier(0);
  __builtin_amdgcn_s_barrier();
  __builtin_amdgcn_sched_barrier(0);
}

// tanh-form GELU: v * t/(t+1), t = exp(2u), u = 0.79788456*(v + 0.044715 v^3)
DEV float gelu_fast(float v) {
  float u = 0.7978845608f * (v + 0.044715f * v * v * v);
  float t = exp2f(u * 2.8853900817779268f);
  float r = __builtin_amdgcn_rcpf(t + 1.0f);
  return v * t * r;
}

// ---- fused: fp32->bf16 weight convert (blocks 0..12287) + LN1 (blocks 12288..16383) ----
__global__ __launch_bounds__(256) void f2b4_ln_kernel(const float* __restrict__ s0,
                                                      const float* __restrict__ s1,
                                                      const float* __restrict__ s2,
                                                      const float* __restrict__ s3,
                                                      bf16* __restrict__ d0, bf16* __restrict__ d1,
                                                      bf16* __restrict__ d2, bf16* __restrict__ d3,
                                                      int n0, int n1, int n2, int n3,
                                                      const float* __restrict__ xin,
                                                      const float* __restrict__ g,
                                                      const float* __restrict__ b,
                                                      bf16* __restrict__ xout) {
  const int tid = threadIdx.x;
  if (blockIdx.x < 12288) {
    int i = (blockIdx.x * 256 + tid) * 4;
    const float* s;
    bf16* d;
    int off;
    if (i < n0) { s = s0; d = d0; off = i; }
    else if (i < n0 + n1) { s = s1; d = d1; off = i - n0; }
    else if (i < n0 + n1 + n2) { s = s2; d = d2; off = i - n0 - n1; }
    else if (i < n0 + n1 + n2 + n3) { s = s3; d = d3; off = i - n0 - n1 - n2; }
    else return;
    float4 v = *(const float4*)(s + off);
    bf16x4 pk;
    pk[0] = (bf16)v.x; pk[1] = (bf16)v.y; pk[2] = (bf16)v.z; pk[3] = (bf16)v.w;
    *(bf16x4*)(d + off) = pk;
    return;
  }
  // ---- LayerNorm(x) row ----
  const int row = blockIdx.x - 12288;
  float4 v = ((const float4*)(xin + (size_t)row * 1024))[tid];
  float sum1 = v.x + v.y + v.z + v.w;
  float sumq = v.x * v.x + v.y * v.y + v.z * v.z + v.w * v.w;
#pragma unroll
  for (int off = 1; off < 64; off <<= 1) {
    sum1 += __shfl_xor(sum1, off);
    sumq += __shfl_xor(sumq, off);
  }
  __shared__ float red[8];
  int w = tid >> 6, lane = tid & 63;
  if (lane == 0) { red[w] = sum1; red[4 + w] = sumq; }
  __syncthreads();
  sum1 = red[0] + red[1] + red[2] + red[3];
  sumq = red[4] + red[5] + red[6] + red[7];
  const float mean = sum1 * (1.f / 1024.f);
  const float var = sumq * (1.f / 1024.f) - mean * mean;
  const float rstd = rsqrtf(var + 1e-5f);
  float4 gv = ((const float4*)g)[tid];
  float4 bv = ((const float4*)b)[tid];
  bf16x4 pk;
  pk[0] = (bf16)((v.x - mean) * rstd * gv.x + bv.x);
  pk[1] = (bf16)((v.y - mean) * rstd * gv.y + bv.y);
  pk[2] = (bf16)((v.z - mean) * rstd * gv.z + bv.z);
  pk[3] = (bf16)((v.w - mean) * rstd * gv.w + bv.w);
  *(bf16x4*)(xout + (size_t)row * 1024 + tid * 4) = pk;
}

// ---------------- LayerNorm bf16-in -> bf16 out, row = 1024 ----------------
__global__ __launch_bounds__(256) void ln_kernel_b(const bf16* __restrict__ in,
                                                   const float* __restrict__ g,
                                                   const float* __restrict__ b,
                                                   bf16* __restrict__ out) {
  const int row = blockIdx.x;
  const int tid = threadIdx.x;
  bf16x4 vb = ((const bf16x4*)(in + (size_t)row * 1024))[tid];
  float4 v;
  v.x = (float)vb[0]; v.y = (float)vb[1]; v.z = (float)vb[2]; v.w = (float)vb[3];
  float sum1 = v.x + v.y + v.z + v.w;
  float sumq = v.x * v.x + v.y * v.y + v.z * v.z + v.w * v.w;
#pragma unroll
  for (int off = 1; off < 64; off <<= 1) {
    sum1 += __shfl_xor(sum1, off);
    sumq += __shfl_xor(sumq, off);
  }
  __shared__ float red[8];
  int w = tid >> 6, lane = tid & 63;
  if (lane == 0) { red[w] = sum1; red[4 + w] = sumq; }
  __syncthreads();
  sum1 = red[0] + red[1] + red[2] + red[3];
  sumq = red[4] + red[5] + red[6] + red[7];
  const float mean = sum1 * (1.f / 1024.f);
  const float var = sumq * (1.f / 1024.f) - mean * mean;
  const float rstd = rsqrtf(var + 1e-5f);
  float4 gv = ((const float4*)g)[tid];
  float4 bv = ((const float4*)b)[tid];
  bf16x4 pk;
  pk[0] = (bf16)((v.x - mean) * rstd * gv.x + bv.x);
  pk[1] = (bf16)((v.y - mean) * rstd * gv.y + bv.y);
  pk[2] = (bf16)((v.z - mean) * rstd * gv.z + bv.z);
  pk[3] = (bf16)((v.w - mean) * rstd * gv.w + bv.w);
  *(bf16x4*)(out + (size_t)row * 1024 + tid * 4) = pk;
}

// ---------------- 256x256 deep-pipelined GEMM: C = A * B^T ----------------
// EPI 0: bf16 out. EPI 1: bias + GELU (tanh-form) -> bf16.
template <int EPI>
__global__ __launch_bounds__(512, 2) void gemm256(const bf16* __restrict__ A,
                                                  const bf16* __restrict__ B,
                                                  bf16* __restrict__ outb,
                                                  const float* __restrict__ bias,
                                                  int M, int N, int K, int gridN) {
  __shared__ bf16 As[2][256 * 64];
  __shared__ bf16 Bs[2][256 * 64];
  const int nwg = gridDim.x;
  const int bid = blockIdx.x;
  const int swz = (bid & 7) * (nwg >> 3) + (bid >> 3);  // nwg % 8 == 0 (bijective)
  const int bx = swz % gridN, by = swz / gridN;
  const int brow = by * 256, bcol = bx * 256;
  const int tid = threadIdx.x;
  const int lane = tid & 63, wid = tid >> 6;
  const int wm = wid >> 2, wn = wid & 3;
  const int lr = lane & 15, lk4 = lane >> 4;
  const int strow = tid >> 3, stc = tid & 7;
  const int NT = K >> 6;
  f32x4 acc[8][4] = {};

#define STAGE(tt, bb)                                                                   \
  {                                                                                     \
    const int k0_ = (tt)*64;                                                            \
    _Pragma("unroll") for (int s_ = 0; s_ < 4; ++s_) {                                  \
      const int r_ = s_ * 64 + strow;                                                   \
      const int g_ = (stc ^ (strow & 7)) * 8;                                           \
      async16(A + (size_t)(brow + r_) * K + k0_ + g_, &As[bb][r_ * 64 + stc * 8]);      \
      async16(B + (size_t)(bcol + r_) * K + k0_ + g_, &Bs[bb][r_ * 64 + stc * 8]);      \
    }                                                                                   \
  }

  STAGE(0, 0);
  STAGE(1, 1);
  asm volatile("s_waitcnt vmcnt(8)" ::: "memory");
  wg_barrier();

  for (int t = 0; t < NT; ++t) {
    const int cur = t & 1;
    bf16x8 af[8][2], bfr[4][2];
#pragma unroll
    for (int m = 0; m < 8; ++m)
#pragma unroll
      for (int kk = 0; kk < 2; ++kk) {
        const int row = wm * 128 + m * 16 + lr;
        const int kc = kk * 4 + lk4;
        af[m][kk] = *(const bf16x8*)&As[cur][row * 64 + ((kc ^ (row & 7)) * 8)];
      }
#pragma unroll
    for (int n = 0; n < 4; ++n)
#pragma unroll
      for (int kk = 0; kk < 2; ++kk) {
        const int row = wn * 64 + n * 16 + lr;
        const int kc = kk * 4 + lk4;
        bfr[n][kk] = *(const bf16x8*)&Bs[cur][row * 64 + ((kc ^ (row & 7)) * 8)];
      }
    asm volatile("s_waitcnt lgkmcnt(0)" ::: "memory");
    wg_barrier();
    if (t + 2 < NT) STAGE(t + 2, cur);
    __builtin_amdgcn_s_setprio(1);
#pragma unroll
    for (int m = 0; m < 8; ++m)
#pragma unroll
      for (int n = 0; n < 4; ++n) {
        acc[m][n] = __builtin_amdgcn_mfma_f32_16x16x32_bf16(af[m][0], bfr[n][0], acc[m][n], 0, 0, 0);
        acc[m][n] = __builtin_amdgcn_mfma_f32_16x16x32_bf16(af[m][1], bfr[n][1], acc[m][n], 0, 0, 0);
      }
    __builtin_amdgcn_s_setprio(0);
    if (t + 1 < NT) {
      if (t + 2 < NT) {
        asm volatile("s_waitcnt vmcnt(8)" ::: "memory");
      } else {
        asm volatile("s_waitcnt vmcnt(0)" ::: "memory");
      }
      wg_barrier();
    }
  }
#undef STAGE
  const int r0 = brow + wm * 128 + lk4 * 4;
  const int c0 = bcol + wn * 64 + lr;
  float bias_v[4];
  if (EPI == 1) {
#pragma unroll
    for (int n = 0; n < 4; ++n) bias_v[n] = bias[c0 + n * 16];
  }
#pragma unroll
  for (int m = 0; m < 8; ++m)
#pragma unroll
    for (int n = 0; n < 4; ++n)
#pragma unroll
      for (int j = 0; j < 4; ++j) {
        const int r = r0 + m * 16 + j;
        const int c = c0 + n * 16;
        float v = acc[m][n][j];
        if (EPI == 1) {
          v = gelu_fast(v + bias_v[n]);
        }
        outb[(size_t)r * N + c] = (bf16)v;
      }
}

// ---------------- 128x128 GEMM, 8 waves = 2M x 2N x 2K-slices ----------------
// EPI 0 (proj): outb = (bf16)(acc + bias + residf)   [fp32 residual in, bf16 out]
// EPI 1 (FC2):  outf = acc + bias + (float)residb    [bf16 residual in, fp32 out]
template <int EPI>
__global__ __launch_bounds__(512, 2) void gemm128(const bf16* __restrict__ A,
                                                  const bf16* __restrict__ B,
                                                  bf16* __restrict__ outb,
                                                  float* __restrict__ outf,
                                                  const float* __restrict__ bias,
                                                  const float* __restrict__ residf,
                                                  const bf16* __restrict__ residb,
                                                  int M, int N, int K, int gridN) {
  __shared__ bf16 As[2][128 * 64];
  __shared__ bf16 Bs[2][128 * 64];
  const int nwg = gridDim.x;
  const int bid = blockIdx.x;
  const int swz = (bid & 7) * (nwg >> 3) + (bid >> 3);  // nwg % 8 == 0
  const int bx = swz % gridN, by = swz / gridN;
  const int brow = by * 128, bcol = bx * 128;
  const int tid = threadIdx.x;
  const int lane = tid & 63, wid = tid >> 6;
  const int wk = wid & 1, wn = (wid >> 1) & 1, wm = wid >> 2;  // 2K x 2N x 2M
  const int lr = lane & 15, lk4 = lane >> 4;
  const int strow = tid >> 3, stc = tid & 7;
  const int NT = K >> 6;
  f32x4 acc[4][4] = {};

#define STAGE1(tt, bb)                                                                  \
  {                                                                                     \
    const int k0_ = (tt)*64;                                                            \
    _Pragma("unroll") for (int s_ = 0; s_ < 2; ++s_) {                                  \
      const int r_ = s_ * 64 + strow;                                                   \
      const int g_ = (stc ^ (strow & 7)) * 8;                                           \
      async16(A + (size_t)(brow + r_) * K + k0_ + g_, &As[bb][r_ * 64 + stc * 8]);      \
      async16(B + (size_t)(bcol + r_) * K + k0_ + g_, &Bs[bb][r_ * 64 + stc * 8]);      \
    }                                                                                   \
  }

  STAGE1(0, 0);
  STAGE1(1, 1);
  asm volatile("s_waitcnt vmcnt(4)" ::: "memory");
  wg_barrier();

  const int kc = wk * 4 + lk4;  // this wave's K-half
  for (int t = 0; t < NT; ++t) {
    const int cur = t & 1;
    bf16x8 af[4], bfr[4];
#pragma unroll
    for (int m = 0; m < 4; ++m) {
      const int row = wm * 64 + m * 16 + lr;
      af[m] = *(const bf16x8*)&As[cur][row * 64 + ((kc ^ (row & 7)) * 8)];
    }
#pragma unroll
    for (int n = 0; n < 4; ++n) {
      const int row = wn * 64 + n * 16 + lr;
      bfr[n] = *(const bf16x8*)&Bs[cur][row * 64 + ((kc ^ (row & 7)) * 8)];
    }
    asm volatile("s_waitcnt lgkmcnt(0)" ::: "memory");
    wg_barrier();
    if (t + 2 < NT) STAGE1(t + 2, cur);
    __builtin_amdgcn_s_setprio(1);
#pragma unroll
    for (int m = 0; m < 4; ++m)
#pragma unroll
      for (int n = 0; n < 4; ++n)
        acc[m][n] = __builtin_amdgcn_mfma_f32_16x16x32_bf16(af[m], bfr[n], acc[m][n], 0, 0, 0);
    __builtin_amdgcn_s_setprio(0);
    if (t + 1 < NT) {
      if (t + 2 < NT) {
        asm volatile("s_waitcnt vmcnt(4)" ::: "memory");
      } else {
        asm volatile("s_waitcnt vmcnt(0)" ::: "memory");
      }
      wg_barrier();
    }
  }
#undef STAGE1
  // ---- cross-K reduction through LDS (As/Bs now free) ----
  __syncthreads();
  {
    const int r = wm * 2 + wn;
    float* reg = (r < 2) ? ((float*)&As[0][0] + r * 4096)
                         : ((float*)&Bs[0][0] + (r - 2) * 4096);
    if (wk == 1) {
#pragma unroll
      for (int m = 0; m < 4; ++m)
#pragma unroll
        for (int n = 0; n < 4; ++n)
#pragma unroll
          for (int j = 0; j < 4; ++j)
            reg[(m * 16 + n * 4 + j) * 64 + lane] = acc[m][n][j];
    }
    __syncthreads();
    if (wk == 0) {
      const int r0 = brow + wm * 64 + lk4 * 4;
      const int c0 = bcol + wn * 64 + lr;
#pragma unroll
      for (int m = 0; m < 4; ++m)
#pragma unroll
        for (int n = 0; n < 4; ++n) {
          const int c = c0 + n * 16;
          const float bv = bias[c];
#pragma unroll
          for (int j = 0; j < 4; ++j) {
            const int rr = r0 + m * 16 + j;
            float v = acc[m][n][j] + reg[(m * 16 + n * 4 + j) * 64 + lane] + bv;
            if (EPI == 0) {
              outb[(size_t)rr * N + c] = (bf16)(v + residf[(size_t)rr * N + c]);
            } else {
              outf[(size_t)rr * N + c] = v + (float)residb[(size_t)rr * N + c];
            }
          }
        }
    }
  }
}

// ---------------- Flash attention (QBLK=128, 8 waves; unroll-2, hoisted addrs) --------
__global__ __launch_bounds__(512, 4) void flash_kernel(const bf16* __restrict__ qkv,
                                                       bf16* __restrict__ out) {
  const int bid = blockIdx.x;                 // 0..511
  const int swz = (bid & 7) * 64 + (bid >> 3);  // XCD-chunked (512 = 8*64, bijective)
  const int qt = swz & 15;
  const int bh = swz >> 4;
  const int b = bh >> 4, h = bh & 15;
  const int tid = threadIdx.x;
  const int lane = tid & 63, w = tid >> 6;
  const int lr = lane & 15, lk4 = lane >> 4;
  const bf16* Qp = qkv + (size_t)(b * 2048) * 3072 + h * 64;
  const bf16* Kp = Qp + 1024;
  const bf16* Vp = Qp + 2048;
  __shared__ bf16 Ks[2][64 * 64];
  __shared__ bf16 VTs[2][64 * 64];
  __shared__ bf16 Ps[128 * 64 + 4096];  // +8KB pad -> 56KB total LDS
  const int qw0 = qt * 128 + w * 16;
  const float SC = 0.125f * 1.44269504f;
  const float THRU = 8.0f / SC;
  bf16x8 qf[2];
#pragma unroll
  for (int kk = 0; kk < 2; ++kk)
    qf[kk] = *(const bf16x8*)(Qp + (size_t)(qw0 + lr) * 3072 + kk * 32 + lk4 * 8);
  f32x4 o[4] = {};
  float mrun = -1e30f, lrun = 0.f;
  const int sr = tid >> 3, sc8 = tid & 7;
  const int vd = tid & 63, vkc = (tid >> 6) * 8;
  const int vch = tid >> 6;
  const int prow = (w * 16 + lr) * 64;
  int koff[4][2], pw[4], pr[2];
#pragma unroll
  for (int n = 0; n < 4; ++n) {
#pragma unroll
    for (int kk = 0; kk < 2; ++kk)
      koff[n][kk] = (n * 16 + lr) * 64 + (((kk * 4 + lk4) ^ (lr & 7)) * 8);
    pw[n] = prow + (((n * 2 + (lk4 >> 1)) ^ (lr & 7)) * 8) + (lk4 & 1) * 4;
  }
#pragma unroll
  for (int kk = 0; kk < 2; ++kk) pr[kk] = prow + (((kk * 4 + lk4) ^ (lr & 7)) * 8);
  const int kso = sc8 ^ (sr & 7);
  const int kdst = sr * 64 + sc8 * 8;
  const int vdst = vd * 64 + ((vch ^ (vd & 7)) * 8);
  const bf16* Kst = Kp + (size_t)64 * 3072;
  const bf16* Vst = Vp + (size_t)64 * 3072;
  const int ksrc = sr * 3072 + kso * 8;
  const int vsrc = vkc * 3072 + vd;
  bf16 vv[8];
  async16(Kp + ksrc, &Ks[0][kdst]);
#pragma unroll
  for (int j = 0; j < 8; ++j) vv[j] = Vp[vsrc + j * 3072];
  {
    bf16x8 a;
#pragma unroll
    for (int j = 0; j < 8; ++j) a[j] = vv[j];
    *(bf16x8*)&VTs[0][vdst] = a;
  }
  __syncthreads();

#define FTILE(CUR, PREF)                                                                \
  {                                                                                     \
    if (PREF) {                                                                         \
      async16(Kst + ksrc, &Ks[CUR ^ 1][kdst]);                                          \
      _Pragma("unroll") for (int j = 0; j < 8; ++j) vv[j] = Vst[vsrc + j * 3072];       \
    }                                                                                   \
    f32x4 st[4] = {};                                                                   \
    __builtin_amdgcn_s_setprio(1);                                                      \
    _Pragma("unroll") for (int n = 0; n < 4; ++n)                                       \
      _Pragma("unroll") for (int kk = 0; kk < 2; ++kk) {                                \
        bf16x8 kf = *(const bf16x8*)&Ks[CUR][koff[n][kk]];                              \
        st[n] = __builtin_amdgcn_mfma_f32_16x16x32_bf16(kf, qf[kk], st[n], 0, 0, 0);    \
      }                                                                                 \
    __builtin_amdgcn_s_setprio(0);                                                      \
    float m01 = fmaxf(fmaxf(st[0][0], st[0][1]), fmaxf(st[0][2], st[0][3]));            \
    float m23 = fmaxf(fmaxf(st[1][0], st[1][1]), fmaxf(st[1][2], st[1][3]));            \
    float m45 = fmaxf(fmaxf(st[2][0], st[2][1]), fmaxf(st[2][2], st[2][3]));            \
    float m67 = fmaxf(fmaxf(st[3][0], st[3][1]), fmaxf(st[3][2], st[3][3]));            \
    float mx = fmaxf(fmaxf(m01, m23), fmaxf(m45, m67));                                 \
    mx = fmaxf(mx, __shfl_xor(mx, 16));                                                 \
    mx = fmaxf(mx, __shfl_xor(mx, 32));                                                 \
    const bool skip = __all(mx <= mrun + THRU);                                         \
    const float mn = skip ? mrun : fmaxf(mrun, mx);                                     \
    const float mnS = mn * SC;                                                          \
    float rs = 0.f;                                                                     \
    _Pragma("unroll") for (int n = 0; n < 4; ++n) {                                     \
      float p0 = exp2f(fmaf(st[n][0], SC, -mnS));                                       \
      float p1 = exp2f(fmaf(st[n][1], SC, -mnS));                                       \
      float p2 = exp2f(fmaf(st[n][2], SC, -mnS));                                       \
      float p3 = exp2f(fmaf(st[n][3], SC, -mnS));                                       \
      rs += (p0 + p1) + (p2 + p3);                                                      \
      bf16x4 pk;                                                                        \
      pk[0] = (bf16)p0; pk[1] = (bf16)p1; pk[2] = (bf16)p2; pk[3] = (bf16)p3;           \
      *(bf16x4*)&Ps[pw[n]] = pk;                                                        \
    }                                                                                   \
    rs += __shfl_xor(rs, 16);                                                           \
    rs += __shfl_xor(rs, 32);                                                           \
    if (!skip) {                                                                        \
      const float alpha = exp2f(fmaf(mrun, SC, -mnS));                                  \
      lrun = lrun * alpha + rs;                                                         \
      mrun = mn;                                                                        \
      _Pragma("unroll") for (int c = 0; c < 4; ++c)                                     \
        _Pragma("unroll") for (int j = 0; j < 4; ++j) o[c][j] *= alpha;                 \
    } else {                                                                            \
      lrun += rs;                                                                       \
    }                                                                                   \
    bf16x8 pb[2];                                                                       \
    _Pragma("unroll") for (int kk = 0; kk < 2; ++kk)                                    \
      pb[kk] = *(const bf16x8*)&Ps[pr[kk]];                                             \
    __builtin_amdgcn_s_setprio(1);                                                      \
    _Pragma("unroll") for (int c = 0; c < 4; ++c)                                       \
      _Pragma("unroll") for (int kk = 0; kk < 2; ++kk) {                                \
        bf16x8 vfr = *(const bf16x8*)&VTs[CUR][koff[c][kk]];                            \
        o[c] = __builtin_amdgcn_mfma_f32_16x16x32_bf16(vfr, pb[kk], o[c], 0, 0, 0);     \
      }                                                                                 \
    __builtin_amdgcn_s_setprio(0);                                                      \
    if (PREF) {                                                                         \
      bf16x8 a;                                                                         \
      _Pragma("unroll") for (int j = 0; j < 8; ++j) a[j] = vv[j];                       \
      *(bf16x8*)&VTs[CUR ^ 1][vdst] = a;                                                \
      Kst += (size_t)64 * 3072;                                                         \
      Vst += (size_t)64 * 3072;                                                         \
    }                                                                                   \
    __syncthreads();                                                                    \
  }

  for (int tt = 0; tt < 16; ++tt) {
    FTILE(0, true);
    FTILE(1, (tt < 15));
  }
#undef FTILE

  const float inv = 1.f / lrun;
#pragma unroll
  for (int c = 0; c < 4; ++c) {
    bf16x4 ov;
#pragma unroll
    for (int j = 0; j < 4; ++j) ov[j] = (bf16)(o[c][j] * inv);
    *(bf16x4*)&out[(size_t)(b * 2048 + qw0 + lr) * 1024 + h * 64 + c * 16 + lk4 * 4] = ov;
  }
}

// ---------------- launch ----------------
extern "C" void kernel_launch(void* const* d_in, const int* in_sizes, int n_in,
                              void* d_out, int out_size, void* d_ws, size_t ws_size,
                              hipStream_t stream) {
  const float* x      = (const float*)d_in[0];
  const float* w_qkv  = (const float*)d_in[1];
  const float* w_proj = (const float*)d_in[2];
  const float* b_proj = (const float*)d_in[3];
  const float* ln1_g  = (const float*)d_in[4];
  const float* ln1_b  = (const float*)d_in[5];
  const float* ln2_g  = (const float*)d_in[6];
  const float* ln2_b  = (const float*)d_in[7];
  const float* w_fc1  = (const float*)d_in[8];
  const float* b_fc1  = (const float*)d_in[9];
  const float* w_fc2  = (const float*)d_in[10];
  const float* b_fc2  = (const float*)d_in[11];

  char* W = (char*)d_ws;
  bf16* wqkvb = (bf16*)(W + 0);                    //  6,291,456
  bf16* wprojb = (bf16*)(W + 6291456);             //  2,097,152
  bf16* wfc1b = (bf16*)(W + 8388608);              //  8,388,608
  bf16* wfc2b = (bf16*)(W + 16777216);             //  8,388,608
  bf16* xn    = (bf16*)(W + 25165824);             //  8,388,608
  bf16* qkvb  = (bf16*)(W + 33554432);             // 25,165,824
  bf16* attnb = (bf16*)(W + 58720256);             //  8,388,608
  bf16* x2b   = (bf16*)(W + 67108864);             //  8,388,608
  bf16* hbuf  = (bf16*)(W + 83886080);             // 33,554,432
  float* outf = (float*)d_out;

  // fused: weight convert (12288 blocks) + LN1 (4096 blocks)
  f2b4_ln_kernel<<<16384, 256, 0, stream>>>(w_qkv, w_proj, w_fc1, w_fc2,
                                            wqkvb, wprojb, wfc1b, wfc2b,
                                            3145728, 1048576, 4194304, 4194304,
                                            x, ln1_g, ln1_b, xn);

  // QKV GEMM (256² deep-pipeline, grid 12x16=192)
  gemm256<0><<<192, 512, 0, stream>>>(xn, wqkvb, qkvb, nullptr, 4096, 3072, 1024, 12);
  // attention (QBLK=128, 8 waves, XCD-chunked 1-D grid)
  flash_kernel<<<512, 512, 0, stream>>>(qkvb, attnb);
  // proj + bias + residual(x fp32) -> x2b bf16 (128² split-K, grid 32x8=256)
  gemm128<0><<<256, 512, 0, stream>>>(attnb, wprojb, x2b, nullptr, b_proj, x, nullptr,
                                      4096, 1024, 1024, 8);
  // LN2 (bf16 in)
  ln_kernel_b<<<4096, 256, 0, stream>>>(x2b, ln2_g, ln2_b, xn);
  // FC1 + bias + GELU (256² deep-pipeline, grid 16x16=256)
  gemm256<1><<<256, 512, 0, stream>>>(xn, wfc1b, hbuf, b_fc1, 4096, 4096, 1024, 16);
  // FC2 + bias + residual(x2b bf16) -> out fp32 (128² split-K, grid 32x8=256)
  gemm128<1><<<256, 512, 0, stream>>>(hbuf, wfc2b, nullptr, outf, b_fc2, nullptr, x2b,
                                      4096, 1024, 4096, 8);
}

// Round 20
// 232.376 us; speedup vs baseline: 1.0571x; 1.0100x over previous
//
#include <hip/hip_runtime.h>
#include <hip/hip_bf16.h>
#include <math.h>

typedef __bf16 bf16;
typedef __attribute__((ext_vector_type(8))) __bf16 bf16x8;
typedef __attribute__((ext_vector_type(4))) __bf16 bf16x4;
typedef __attribute__((ext_vector_type(4))) float f32x4;

#define DEV static __device__ __forceinline__

typedef const void __attribute__((address_space(1)))* gptr_t;
typedef void __attribute__((address_space(3)))* lptr_t;

DEV void async16(const void* g, void* l) {
  __builtin_amdgcn_global_load_lds((gptr_t)g, (lptr_t)l, 16, 0, 0);
}

DEV void wg_barrier() {
  __builtin_amdgcn_sched_barrier(0);
  __builtin_amdgcn_s_barrier();
  __builtin_amdgcn_sched_barrier(0);
}

// tanh-form GELU: v * t/(t+1), t = exp(2u), u = 0.79788456*(v + 0.044715 v^3)
DEV float gelu_fast(float v) {
  float u = 0.7978845608f * (v + 0.044715f * v * v * v);
  float t = exp2f(u * 2.8853900817779268f);
  float r = __builtin_amdgcn_rcpf(t + 1.0f);
  return v * t * r;
}

// ---- fused: fp32->bf16 weight convert (blocks 0..12287) + LN1 (blocks 12288..16383) ----
__global__ __launch_bounds__(256) void f2b4_ln_kernel(const float* __restrict__ s0,
                                                      const float* __restrict__ s1,
                                                      const float* __restrict__ s2,
                                                      const float* __restrict__ s3,
                                                      bf16* __restrict__ d0, bf16* __restrict__ d1,
                                                      bf16* __restrict__ d2, bf16* __restrict__ d3,
                                                      int n0, int n1, int n2, int n3,
                                                      const float* __restrict__ xin,
                                                      const float* __restrict__ g,
                                                      const float* __restrict__ b,
                                                      bf16* __restrict__ xout) {
  const int tid = threadIdx.x;
  if (blockIdx.x < 12288) {
    int i = (blockIdx.x * 256 + tid) * 4;
    const float* s;
    bf16* d;
    int off;
    if (i < n0) { s = s0; d = d0; off = i; }
    else if (i < n0 + n1) { s = s1; d = d1; off = i - n0; }
    else if (i < n0 + n1 + n2) { s = s2; d = d2; off = i - n0 - n1; }
    else if (i < n0 + n1 + n2 + n3) { s = s3; d = d3; off = i - n0 - n1 - n2; }
    else return;
    float4 v = *(const float4*)(s + off);
    bf16x4 pk;
    pk[0] = (bf16)v.x; pk[1] = (bf16)v.y; pk[2] = (bf16)v.z; pk[3] = (bf16)v.w;
    *(bf16x4*)(d + off) = pk;
    return;
  }
  // ---- LayerNorm(x) row ----
  const int row = blockIdx.x - 12288;
  float4 v = ((const float4*)(xin + (size_t)row * 1024))[tid];
  float sum1 = v.x + v.y + v.z + v.w;
  float sumq = v.x * v.x + v.y * v.y + v.z * v.z + v.w * v.w;
#pragma unroll
  for (int off = 1; off < 64; off <<= 1) {
    sum1 += __shfl_xor(sum1, off);
    sumq += __shfl_xor(sumq, off);
  }
  __shared__ float red[8];
  int w = tid >> 6, lane = tid & 63;
  if (lane == 0) { red[w] = sum1; red[4 + w] = sumq; }
  __syncthreads();
  sum1 = red[0] + red[1] + red[2] + red[3];
  sumq = red[4] + red[5] + red[6] + red[7];
  const float mean = sum1 * (1.f / 1024.f);
  const float var = sumq * (1.f / 1024.f) - mean * mean;
  const float rstd = rsqrtf(var + 1e-5f);
  float4 gv = ((const float4*)g)[tid];
  float4 bv = ((const float4*)b)[tid];
  bf16x4 pk;
  pk[0] = (bf16)((v.x - mean) * rstd * gv.x + bv.x);
  pk[1] = (bf16)((v.y - mean) * rstd * gv.y + bv.y);
  pk[2] = (bf16)((v.z - mean) * rstd * gv.z + bv.z);
  pk[3] = (bf16)((v.w - mean) * rstd * gv.w + bv.w);
  *(bf16x4*)(xout + (size_t)row * 1024 + tid * 4) = pk;
}

// ---------------- LayerNorm bf16-in -> bf16 out, row = 1024 ----------------
__global__ __launch_bounds__(256) void ln_kernel_b(const bf16* __restrict__ in,
                                                   const float* __restrict__ g,
                                                   const float* __restrict__ b,
                                                   bf16* __restrict__ out) {
  const int row = blockIdx.x;
  const int tid = threadIdx.x;
  bf16x4 vb = ((const bf16x4*)(in + (size_t)row * 1024))[tid];
  float4 v;
  v.x = (float)vb[0]; v.y = (float)vb[1]; v.z = (float)vb[2]; v.w = (float)vb[3];
  float sum1 = v.x + v.y + v.z + v.w;
  float sumq = v.x * v.x + v.y * v.y + v.z * v.z + v.w * v.w;
#pragma unroll
  for (int off = 1; off < 64; off <<= 1) {
    sum1 += __shfl_xor(sum1, off);
    sumq += __shfl_xor(sumq, off);
  }
  __shared__ float red[8];
  int w = tid >> 6, lane = tid & 63;
  if (lane == 0) { red[w] = sum1; red[4 + w] = sumq; }
  __syncthreads();
  sum1 = red[0] + red[1] + red[2] + red[3];
  sumq = red[4] + red[5] + red[6] + red[7];
  const float mean = sum1 * (1.f / 1024.f);
  const float var = sumq * (1.f / 1024.f) - mean * mean;
  const float rstd = rsqrtf(var + 1e-5f);
  float4 gv = ((const float4*)g)[tid];
  float4 bv = ((const float4*)b)[tid];
  bf16x4 pk;
  pk[0] = (bf16)((v.x - mean) * rstd * gv.x + bv.x);
  pk[1] = (bf16)((v.y - mean) * rstd * gv.y + bv.y);
  pk[2] = (bf16)((v.z - mean) * rstd * gv.z + bv.z);
  pk[3] = (bf16)((v.w - mean) * rstd * gv.w + bv.w);
  *(bf16x4*)(out + (size_t)row * 1024 + tid * 4) = pk;
}

// ---------------- 256xBN deep-pipelined GEMM: C = A * B^T ----------------
// NF = BN/64 (4 -> 256-wide, 3 -> 192-wide for exact 256-block grids).
// EPI 0: bf16 out. EPI 1: bias + GELU (tanh-form) -> bf16.
template <int EPI, int NF>
__global__ __launch_bounds__(512, 2) void gemm256(const bf16* __restrict__ A,
                                                  const bf16* __restrict__ B,
                                                  bf16* __restrict__ outb,
                                                  const float* __restrict__ bias,
                                                  int M, int N, int K, int gridN) {
  constexpr int BN = NF * 64;
  __shared__ bf16 As[2][256 * 64];
  __shared__ bf16 Bs[2][BN * 64];
  const int nwg = gridDim.x;
  const int bid = blockIdx.x;
  const int swz = (bid & 7) * (nwg >> 3) + (bid >> 3);  // nwg % 8 == 0 (bijective)
  const int bx = swz % gridN, by = swz / gridN;
  const int brow = by * 256, bcol = bx * BN;
  const int tid = threadIdx.x;
  const int lane = tid & 63, wid = tid >> 6;
  const int wm = wid >> 2, wn = wid & 3;
  const int lr = lane & 15, lk4 = lane >> 4;
  const int strow = tid >> 3, stc = tid & 7;
  const int NT = K >> 6;
  f32x4 acc[8][NF] = {};

#define STAGE(tt, bb)                                                                   \
  {                                                                                     \
    const int k0_ = (tt)*64;                                                            \
    _Pragma("unroll") for (int s_ = 0; s_ < 4; ++s_) {                                  \
      const int r_ = s_ * 64 + strow;                                                   \
      const int g_ = (stc ^ (strow & 7)) * 8;                                           \
      async16(A + (size_t)(brow + r_) * K + k0_ + g_, &As[bb][r_ * 64 + stc * 8]);      \
    }                                                                                   \
    _Pragma("unroll") for (int s_ = 0; s_ < NF; ++s_) {                                 \
      const int r_ = s_ * 64 + strow;                                                   \
      const int g_ = (stc ^ (strow & 7)) * 8;                                           \
      async16(B + (size_t)(bcol + r_) * K + k0_ + g_, &Bs[bb][r_ * 64 + stc * 8]);      \
    }                                                                                   \
  }

#define WAIT_L()                                                                        \
  if (NF == 4) { asm volatile("s_waitcnt vmcnt(8)" ::: "memory"); }                     \
  else { asm volatile("s_waitcnt vmcnt(7)" ::: "memory"); }

  STAGE(0, 0);
  STAGE(1, 1);
  WAIT_L();
  wg_barrier();

  for (int t = 0; t < NT; ++t) {
    const int cur = t & 1;
    bf16x8 af[8][2], bfr[NF][2];
#pragma unroll
    for (int m = 0; m < 8; ++m)
#pragma unroll
      for (int kk = 0; kk < 2; ++kk) {
        const int row = wm * 128 + m * 16 + lr;
        const int kc = kk * 4 + lk4;
        af[m][kk] = *(const bf16x8*)&As[cur][row * 64 + ((kc ^ (row & 7)) * 8)];
      }
#pragma unroll
    for (int n = 0; n < NF; ++n)
#pragma unroll
      for (int kk = 0; kk < 2; ++kk) {
        const int row = wn * (NF * 16) + n * 16 + lr;
        const int kc = kk * 4 + lk4;
        bfr[n][kk] = *(const bf16x8*)&Bs[cur][row * 64 + ((kc ^ (row & 7)) * 8)];
      }
    asm volatile("s_waitcnt lgkmcnt(0)" ::: "memory");
    wg_barrier();
    if (t + 2 < NT) STAGE(t + 2, cur);
    __builtin_amdgcn_s_setprio(1);
#pragma unroll
    for (int m = 0; m < 8; ++m)
#pragma unroll
      for (int n = 0; n < NF; ++n) {
        acc[m][n] = __builtin_amdgcn_mfma_f32_16x16x32_bf16(af[m][0], bfr[n][0], acc[m][n], 0, 0, 0);
        acc[m][n] = __builtin_amdgcn_mfma_f32_16x16x32_bf16(af[m][1], bfr[n][1], acc[m][n], 0, 0, 0);
      }
    __builtin_amdgcn_s_setprio(0);
    if (t + 1 < NT) {
      if (t + 2 < NT) {
        WAIT_L();
      } else {
        asm volatile("s_waitcnt vmcnt(0)" ::: "memory");
      }
      wg_barrier();
    }
  }
#undef STAGE
#undef WAIT_L
  const int r0 = brow + wm * 128 + lk4 * 4;
  const int c0 = bcol + wn * (NF * 16) + lr;
  float bias_v[NF];
  if (EPI == 1) {
#pragma unroll
    for (int n = 0; n < NF; ++n) bias_v[n] = bias[c0 + n * 16];
  }
#pragma unroll
  for (int m = 0; m < 8; ++m)
#pragma unroll
    for (int n = 0; n < NF; ++n)
#pragma unroll
      for (int j = 0; j < 4; ++j) {
        const int r = r0 + m * 16 + j;
        const int c = c0 + n * 16;
        float v = acc[m][n][j];
        if (EPI == 1) {
          v = gelu_fast(v + bias_v[n]);
        }
        outb[(size_t)r * N + c] = (bf16)v;
      }
}

// ---------------- 128x128 GEMM, 8 waves = 2M x 2N x 2K-slices ----------------
// EPI 0 (proj): outb = (bf16)(acc + bias + residf)   [fp32 residual in, bf16 out]
// EPI 1 (FC2):  outf = acc + bias + (float)residb    [bf16 residual in, fp32 out]
template <int EPI>
__global__ __launch_bounds__(512, 2) void gemm128(const bf16* __restrict__ A,
                                                  const bf16* __restrict__ B,
                                                  bf16* __restrict__ outb,
                                                  float* __restrict__ outf,
                                                  const float* __restrict__ bias,
                                                  const float* __restrict__ residf,
                                                  const bf16* __restrict__ residb,
                                                  int M, int N, int K, int gridN) {
  __shared__ bf16 As[2][128 * 64];
  __shared__ bf16 Bs[2][128 * 64];
  const int nwg = gridDim.x;
  const int bid = blockIdx.x;
  const int swz = (bid & 7) * (nwg >> 3) + (bid >> 3);  // nwg % 8 == 0
  const int bx = swz % gridN, by = swz / gridN;
  const int brow = by * 128, bcol = bx * 128;
  const int tid = threadIdx.x;
  const int lane = tid & 63, wid = tid >> 6;
  const int wk = wid & 1, wn = (wid >> 1) & 1, wm = wid >> 2;  // 2K x 2N x 2M
  const int lr = lane & 15, lk4 = lane >> 4;
  const int strow = tid >> 3, stc = tid & 7;
  const int NT = K >> 6;
  f32x4 acc[4][4] = {};

#define STAGE1(tt, bb)                                                                  \
  {                                                                                     \
    const int k0_ = (tt)*64;                                                            \
    _Pragma("unroll") for (int s_ = 0; s_ < 2; ++s_) {                                  \
      const int r_ = s_ * 64 + strow;                                                   \
      const int g_ = (stc ^ (strow & 7)) * 8;                                           \
      async16(A + (size_t)(brow + r_) * K + k0_ + g_, &As[bb][r_ * 64 + stc * 8]);      \
      async16(B + (size_t)(bcol + r_) * K + k0_ + g_, &Bs[bb][r_ * 64 + stc * 8]);      \
    }                                                                                   \
  }

  STAGE1(0, 0);
  STAGE1(1, 1);
  asm volatile("s_waitcnt vmcnt(4)" ::: "memory");
  wg_barrier();

  const int kc = wk * 4 + lk4;  // this wave's K-half
  for (int t = 0; t < NT; ++t) {
    const int cur = t & 1;
    bf16x8 af[4], bfr[4];
#pragma unroll
    for (int m = 0; m < 4; ++m) {
      const int row = wm * 64 + m * 16 + lr;
      af[m] = *(const bf16x8*)&As[cur][row * 64 + ((kc ^ (row & 7)) * 8)];
    }
#pragma unroll
    for (int n = 0; n < 4; ++n) {
      const int row = wn * 64 + n * 16 + lr;
      bfr[n] = *(const bf16x8*)&Bs[cur][row * 64 + ((kc ^ (row & 7)) * 8)];
    }
    asm volatile("s_waitcnt lgkmcnt(0)" ::: "memory");
    wg_barrier();
    if (t + 2 < NT) STAGE1(t + 2, cur);
    __builtin_amdgcn_s_setprio(1);
#pragma unroll
    for (int m = 0; m < 4; ++m)
#pragma unroll
      for (int n = 0; n < 4; ++n)
        acc[m][n] = __builtin_amdgcn_mfma_f32_16x16x32_bf16(af[m], bfr[n], acc[m][n], 0, 0, 0);
    __builtin_amdgcn_s_setprio(0);
    if (t + 1 < NT) {
      if (t + 2 < NT) {
        asm volatile("s_waitcnt vmcnt(4)" ::: "memory");
      } else {
        asm volatile("s_waitcnt vmcnt(0)" ::: "memory");
      }
      wg_barrier();
    }
  }
#undef STAGE1
  // ---- cross-K reduction through LDS (As/Bs now free) ----
  __syncthreads();
  {
    const int r = wm * 2 + wn;
    float* reg = (r < 2) ? ((float*)&As[0][0] + r * 4096)
                         : ((float*)&Bs[0][0] + (r - 2) * 4096);
    if (wk == 1) {
#pragma unroll
      for (int m = 0; m < 4; ++m)
#pragma unroll
        for (int n = 0; n < 4; ++n)
#pragma unroll
          for (int j = 0; j < 4; ++j)
            reg[(m * 16 + n * 4 + j) * 64 + lane] = acc[m][n][j];
    }
    __syncthreads();
    if (wk == 0) {
      const int r0 = brow + wm * 64 + lk4 * 4;
      const int c0 = bcol + wn * 64 + lr;
#pragma unroll
      for (int m = 0; m < 4; ++m)
#pragma unroll
        for (int n = 0; n < 4; ++n) {
          const int c = c0 + n * 16;
          const float bv = bias[c];
#pragma unroll
          for (int j = 0; j < 4; ++j) {
            const int rr = r0 + m * 16 + j;
            float v = acc[m][n][j] + reg[(m * 16 + n * 4 + j) * 64 + lane] + bv;
            if (EPI == 0) {
              outb[(size_t)rr * N + c] = (bf16)(v + residf[(size_t)rr * N + c]);
            } else {
              outf[(size_t)rr * N + c] = v + (float)residb[(size_t)rr * N + c];
            }
          }
        }
    }
  }
}

// ---------------- Flash attention (QBLK=128, 8 waves; unroll-2, hoisted addrs) --------
__global__ __launch_bounds__(512, 4) void flash_kernel(const bf16* __restrict__ qkv,
                                                       bf16* __restrict__ out) {
  const int bid = blockIdx.x;                 // 0..511
  const int swz = (bid & 7) * 64 + (bid >> 3);  // XCD-chunked (512 = 8*64, bijective)
  const int qt = swz & 15;
  const int bh = swz >> 4;
  const int b = bh >> 4, h = bh & 15;
  const int tid = threadIdx.x;
  const int lane = tid & 63, w = tid >> 6;
  const int lr = lane & 15, lk4 = lane >> 4;
  const bf16* Qp = qkv + (size_t)(b * 2048) * 3072 + h * 64;
  const bf16* Kp = Qp + 1024;
  const bf16* Vp = Qp + 2048;
  __shared__ bf16 Ks[2][64 * 64];
  __shared__ bf16 VTs[2][64 * 64];
  __shared__ bf16 Ps[128 * 64 + 4096];  // +8KB pad -> 56KB total LDS
  const int qw0 = qt * 128 + w * 16;
  const float SC = 0.125f * 1.44269504f;
  const float THRU = 8.0f / SC;
  bf16x8 qf[2];
#pragma unroll
  for (int kk = 0; kk < 2; ++kk)
    qf[kk] = *(const bf16x8*)(Qp + (size_t)(qw0 + lr) * 3072 + kk * 32 + lk4 * 8);
  f32x4 o[4] = {};
  float mrun = -1e30f, lrun = 0.f;
  const int sr = tid >> 3, sc8 = tid & 7;
  const int vd = tid & 63, vkc = (tid >> 6) * 8;
  const int vch = tid >> 6;
  const int prow = (w * 16 + lr) * 64;
  int koff[4][2], pw[4], pr[2];
#pragma unroll
  for (int n = 0; n < 4; ++n) {
#pragma unroll
    for (int kk = 0; kk < 2; ++kk)
      koff[n][kk] = (n * 16 + lr) * 64 + (((kk * 4 + lk4) ^ (lr & 7)) * 8);
    pw[n] = prow + (((n * 2 + (lk4 >> 1)) ^ (lr & 7)) * 8) + (lk4 & 1) * 4;
  }
#pragma unroll
  for (int kk = 0; kk < 2; ++kk) pr[kk] = prow + (((kk * 4 + lk4) ^ (lr & 7)) * 8);
  const int kso = sc8 ^ (sr & 7);
  const int kdst = sr * 64 + sc8 * 8;
  const int vdst = vd * 64 + ((vch ^ (vd & 7)) * 8);
  const bf16* Kst = Kp + (size_t)64 * 3072;
  const bf16* Vst = Vp + (size_t)64 * 3072;
  const int ksrc = sr * 3072 + kso * 8;
  const int vsrc = vkc * 3072 + vd;
  bf16 vv[8];
  async16(Kp + ksrc, &Ks[0][kdst]);
#pragma unroll
  for (int j = 0; j < 8; ++j) vv[j] = Vp[vsrc + j * 3072];
  {
    bf16x8 a;
#pragma unroll
    for (int j = 0; j < 8; ++j) a[j] = vv[j];
    *(bf16x8*)&VTs[0][vdst] = a;
  }
  __syncthreads();

#define FTILE(CUR, PREF)                                                                \
  {                                                                                     \
    if (PREF) {                                                                         \
      async16(Kst + ksrc, &Ks[CUR ^ 1][kdst]);                                          \
      _Pragma("unroll") for (int j = 0; j < 8; ++j) vv[j] = Vst[vsrc + j * 3072];       \
    }                                                                                   \
    f32x4 st[4] = {};                                                                   \
    __builtin_amdgcn_s_setprio(1);                                                      \
    _Pragma("unroll") for (int n = 0; n < 4; ++n)                                       \
      _Pragma("unroll") for (int kk = 0; kk < 2; ++kk) {                                \
        bf16x8 kf = *(const bf16x8*)&Ks[CUR][koff[n][kk]];                              \
        st[n] = __builtin_amdgcn_mfma_f32_16x16x32_bf16(kf, qf[kk], st[n], 0, 0, 0);    \
      }                                                                                 \
    __builtin_amdgcn_s_setprio(0);                                                      \
    float m01 = fmaxf(fmaxf(st[0][0], st[0][1]), fmaxf(st[0][2], st[0][3]));            \
    float m23 = fmaxf(fmaxf(st[1][0], st[1][1]), fmaxf(st[1][2], st[1][3]));            \
    float m45 = fmaxf(fmaxf(st[2][0], st[2][1]), fmaxf(st[2][2], st[2][3]));            \
    float m67 = fmaxf(fmaxf(st[3][0], st[3][1]), fmaxf(st[3][2], st[3][3]));            \
    float mx = fmaxf(fmaxf(m01, m23), fmaxf(m45, m67));                                 \
    mx = fmaxf(mx, __shfl_xor(mx, 16));                                                 \
    mx = fmaxf(mx, __shfl_xor(mx, 32));                                                 \
    const bool skip = __all(mx <= mrun + THRU);                                         \
    const float mn = skip ? mrun : fmaxf(mrun, mx);                                     \
    const float mnS = mn * SC;                                                          \
    float rs = 0.f;                                                                     \
    _Pragma("unroll") for (int n = 0; n < 4; ++n) {                                     \
      float p0 = exp2f(fmaf(st[n][0], SC, -mnS));                                       \
      float p1 = exp2f(fmaf(st[n][1], SC, -mnS));                                       \
      float p2 = exp2f(fmaf(st[n][2], SC, -mnS));                                       \
      float p3 = exp2f(fmaf(st[n][3], SC, -mnS));                                       \
      rs += (p0 + p1) + (p2 + p3);                                                      \
      bf16x4 pk;                                                                        \
      pk[0] = (bf16)p0; pk[1] = (bf16)p1; pk[2] = (bf16)p2; pk[3] = (bf16)p3;           \
      *(bf16x4*)&Ps[pw[n]] = pk;                                                        \
    }                                                                                   \
    rs += __shfl_xor(rs, 16);                                                           \
    rs += __shfl_xor(rs, 32);                                                           \
    if (!skip) {                                                                        \
      const float alpha = exp2f(fmaf(mrun, SC, -mnS));                                  \
      lrun = lrun * alpha + rs;                                                         \
      mrun = mn;                                                                        \
      _Pragma("unroll") for (int c = 0; c < 4; ++c)                                     \
        _Pragma("unroll") for (int j = 0; j < 4; ++j) o[c][j] *= alpha;                 \
    } else {                                                                            \
      lrun += rs;                                                                       \
    }                                                                                   \
    bf16x8 pb[2];                                                                       \
    _Pragma("unroll") for (int kk = 0; kk < 2; ++kk)                                    \
      pb[kk] = *(const bf16x8*)&Ps[pr[kk]];                                             \
    __builtin_amdgcn_s_setprio(1);                                                      \
    _Pragma("unroll") for (int c = 0; c < 4; ++c)                                       \
      _Pragma("unroll") for (int kk = 0; kk < 2; ++kk) {                                \
        bf16x8 vfr = *(const bf16x8*)&VTs[CUR][koff[c][kk]];                            \
        o[c] = __builtin_amdgcn_mfma_f32_16x16x32_bf16(vfr, pb[kk], o[c], 0, 0, 0);     \
      }                                                                                 \
    __builtin_amdgcn_s_setprio(0);                                                      \
    if (PREF) {                                                                         \
      bf16x8 a;                                                                         \
      _Pragma("unroll") for (int j = 0; j < 8; ++j) a[j] = vv[j];                       \
      *(bf16x8*)&VTs[CUR ^ 1][vdst] = a;                                                \
      Kst += (size_t)64 * 3072;                                                         \
      Vst += (size_t)64 * 3072;                                                         \
    }                                                                                   \
    __syncthreads();                                                                    \
  }

  for (int tt = 0; tt < 16; ++tt) {
    FTILE(0, true);
    FTILE(1, (tt < 15));
  }
#undef FTILE

  const float inv = 1.f / lrun;
#pragma unroll
  for (int c = 0; c < 4; ++c) {
    bf16x4 ov;
#pragma unroll
    for (int j = 0; j < 4; ++j) ov[j] = (bf16)(o[c][j] * inv);
    *(bf16x4*)&out[(size_t)(b * 2048 + qw0 + lr) * 1024 + h * 64 + c * 16 + lk4 * 4] = ov;
  }
}

// ---------------- launch ----------------
extern "C" void kernel_launch(void* const* d_in, const int* in_sizes, int n_in,
                              void* d_out, int out_size, void* d_ws, size_t ws_size,
                              hipStream_t stream) {
  const float* x      = (const float*)d_in[0];
  const float* w_qkv  = (const float*)d_in[1];
  const float* w_proj = (const float*)d_in[2];
  const float* b_proj = (const float*)d_in[3];
  const float* ln1_g  = (const float*)d_in[4];
  const float* ln1_b  = (const float*)d_in[5];
  const float* ln2_g  = (const float*)d_in[6];
  const float* ln2_b  = (const float*)d_in[7];
  const float* w_fc1  = (const float*)d_in[8];
  const float* b_fc1  = (const float*)d_in[9];
  const float* w_fc2  = (const float*)d_in[10];
  const float* b_fc2  = (const float*)d_in[11];

  char* W = (char*)d_ws;
  bf16* wqkvb = (bf16*)(W + 0);                    //  6,291,456
  bf16* wprojb = (bf16*)(W + 6291456);             //  2,097,152
  bf16* wfc1b = (bf16*)(W + 8388608);              //  8,388,608
  bf16* wfc2b = (bf16*)(W + 16777216);             //  8,388,608
  bf16* xn    = (bf16*)(W + 25165824);             //  8,388,608
  bf16* qkvb  = (bf16*)(W + 33554432);             // 25,165,824
  bf16* attnb = (bf16*)(W + 58720256);             //  8,388,608
  bf16* x2b   = (bf16*)(W + 67108864);             //  8,388,608
  bf16* hbuf  = (bf16*)(W + 83886080);             // 33,554,432
  float* outf = (float*)d_out;

  // fused: weight convert (12288 blocks) + LN1 (4096 blocks)
  f2b4_ln_kernel<<<16384, 256, 0, stream>>>(w_qkv, w_proj, w_fc1, w_fc2,
                                            wqkvb, wprojb, wfc1b, wfc2b,
                                            3145728, 1048576, 4194304, 4194304,
                                            x, ln1_g, ln1_b, xn);

  // QKV GEMM (256x192 deep-pipeline, grid 16x16=256 -> perfect CU fill)
  gemm256<0, 3><<<256, 512, 0, stream>>>(xn, wqkvb, qkvb, nullptr, 4096, 3072, 1024, 16);
  // attention (QBLK=128, 8 waves, XCD-chunked 1-D grid)
  flash_kernel<<<512, 512, 0, stream>>>(qkvb, attnb);
  // proj + bias + residual(x fp32) -> x2b bf16 (128² split-K, grid 32x8=256)
  gemm128<0><<<256, 512, 0, stream>>>(attnb, wprojb, x2b, nullptr, b_proj, x, nullptr,
                                      4096, 1024, 1024, 8);
  // LN2 (bf16 in)
  ln_kernel_b<<<4096, 256, 0, stream>>>(x2b, ln2_g, ln2_b, xn);
  // FC1 + bias + GELU (256² deep-pipeline, grid 16x16=256)
  gemm256<1, 4><<<256, 512, 0, stream>>>(xn, wfc1b, hbuf, b_fc1, 4096, 4096, 1024, 16);
  // FC2 + bias + residual(x2b bf16) -> out fp32 (128² split-K, grid 32x8=256)
  gemm128<1><<<256, 512, 0, stream>>>(hbuf, wfc2b, nullptr, outf, b_fc2, nullptr, x2b,
                                      4096, 1024, 4096, 8);
}